// Round 11
// baseline (1307.588 us; speedup 1.0000x reference)
//
#include <hip/hip_runtime.h>

#define N_NODES 100000
#define N_EDGES 1600000
#define DIM 64
#define BN_EPS 1e-5f

#define BNODES 128                        // nodes per bucket (7 bits)
#define NBUCK ((N_NODES + BNODES - 1) / BNODES)  // 782
#define CAP_RAW 2560                      // raw entries/bucket: mean 2046, +11 sigma
#define CAP_OUT 3584                      // sorted+padded capacity
#define ATILE 3125                        // edges per partition tile
#define ATILES (N_EDGES / ATILE)          // 512 (exact)
#define NBLK 1024                         // grid: 4 blocks/CU x 256 CU (co-resident)
#define NTHR 256
#define NGROUP (N_NODES / 4)              // 25000 gather groups (4 nodes each)
#define NCHUNK (N_NODES / 16)             // 6250 gemm chunks (16 rows each)

typedef __bf16 bf16x8 __attribute__((ext_vector_type(8)));
typedef float floatx4 __attribute__((ext_vector_type(4)));

static __device__ __forceinline__ unsigned short f2bf(float f) {
    unsigned u = __float_as_uint(f);
    u = (u + 0x7FFFu + ((u >> 16) & 1u)) >> 16;
    return (unsigned short)u;
}
static __device__ __forceinline__ float bf2f(unsigned short h) {
    return __uint_as_float(((unsigned)h) << 16);
}

union SMem {
    struct { int hist[NBUCK]; int lbase[NBUCK]; } a;                    // 6.3 KB
    struct { unsigned int raw[CAP_RAW];
             int hist[BNODES]; int sbuf[BNODES];
             int startx[BNODES]; int cursor[BNODES]; } b;               // 12.3 KB
    struct { float red[2][4][64]; } g;                                  // 2 KB
    struct { float scale[64]; float shift[64]; } f;                     // 0.5 KB
    float flat[256];
};

// sense-reversing software grid barrier; all 1024 blocks are co-resident by
// the launch_bounds occupancy contract, so spinning is safe.
static __device__ __forceinline__ void gsync(int* cnt, int* gen) {
    __syncthreads();
    if (threadIdx.x == 0) {
        __threadfence();   // device-scope release of this block's prior writes
        int g = __hip_atomic_load(gen, __ATOMIC_RELAXED, __HIP_MEMORY_SCOPE_AGENT);
        int prev = __hip_atomic_fetch_add(cnt, 1, __ATOMIC_ACQ_REL, __HIP_MEMORY_SCOPE_AGENT);
        if (prev == (int)gridDim.x - 1) {
            __hip_atomic_store(cnt, 0, __ATOMIC_RELAXED, __HIP_MEMORY_SCOPE_AGENT);
            __hip_atomic_fetch_add(gen, 1, __ATOMIC_ACQ_REL, __HIP_MEMORY_SCOPE_AGENT);
        } else {
            while (__hip_atomic_load(gen, __ATOMIC_ACQUIRE, __HIP_MEMORY_SCOPE_AGENT) == g)
                __builtin_amdgcn_s_sleep(2);
        }
        __threadfence();   // acquire side
    }
    __syncthreads();
}

__global__ void __launch_bounds__(NTHR, 4)
fused_kernel(const int* __restrict__ src, const int* __restrict__ dst,
             const float* __restrict__ x, const float* __restrict__ W,
             const float* __restrict__ gamma, const float* __restrict__ beta,
             float* __restrict__ out,
             unsigned short* __restrict__ hb, float* __restrict__ dinv,
             int* __restrict__ rowbeg, int* __restrict__ rowend,
             unsigned int* __restrict__ entries, float* __restrict__ partial,
             int* __restrict__ cur, int* bcnt, int* bgen,
             float* __restrict__ gsum, float* __restrict__ gsumsq,
             int dummyIdx) {
    __shared__ SMem sm;
    int t    = threadIdx.x;
    int blk  = blockIdx.x;
    int lane = t & 63;
    int wv   = t >> 6;
    int gwave = blk * 4 + wv;

    // ---- P1: partition edges into 128-node buckets (blocks 0..511) -------
    if (blk < ATILES) {
        for (int i = t; i < NBUCK; i += NTHR) sm.a.hist[i] = 0;
        __syncthreads();
        int e0 = blk * ATILE, eend = e0 + ATILE;
        for (int e = e0 + t; e < eend; e += NTHR)
            atomicAdd(&sm.a.hist[dst[e] >> 7], 1);
        __syncthreads();
        for (int i = t; i < NBUCK; i += NTHR) {
            int ii = i + (blk * 331) % NBUCK;       // staggered reservation
            if (ii >= NBUCK) ii -= NBUCK;
            int c = sm.a.hist[ii];
            sm.a.lbase[ii] = (c > 0) ? atomicAdd(&cur[ii], c) : 0;
            sm.a.hist[ii] = 0;
        }
        __syncthreads();
        for (int e = e0 + t; e < eend; e += NTHR) { // tile is L2-hot re-read
            int s = src[e], d = dst[e];
            int b = d >> 7;
            int r = atomicAdd(&sm.a.hist[b], 1);
            int pos = sm.a.lbase[b] + r;
            if (pos < CAP_RAW)
                entries[(size_t)b * CAP_OUT + pos] = ((unsigned)s << 7) | (unsigned)(d & 127);
        }
    }
    gsync(bcnt, bgen);

    // ---- P2: in-LDS counting sort per bucket, 8-padded segments ----------
    if (blk < NBUCK) {
        int bucket = blk;
        int node0 = bucket * BNODES;
        int nn = min(BNODES, N_NODES - node0);
        int cnt = min(cur[bucket], CAP_RAW);
        unsigned int* eb = entries + (size_t)bucket * CAP_OUT;
        if (t < BNODES) sm.b.hist[t] = 0;
        __syncthreads();
        for (int i = t; i < cnt; i += NTHR) {
            unsigned int e = eb[i];
            sm.b.raw[i] = e;
            atomicAdd(&sm.b.hist[e & 127], 1);
        }
        __syncthreads();
        int pdeg_t = 0;
        if (t < BNODES) { pdeg_t = (sm.b.hist[t] + 7) & ~7; sm.b.sbuf[t] = pdeg_t; }
        __syncthreads();
        for (int off = 1; off < BNODES; off <<= 1) {
            int add = (t < BNODES && t >= off) ? sm.b.sbuf[t - off] : 0;
            __syncthreads();
            if (t < BNODES) sm.b.sbuf[t] += add;
            __syncthreads();
        }
        if (t < BNODES) {
            int ex = sm.b.sbuf[t] - pdeg_t;
            sm.b.startx[t] = ex;
            sm.b.cursor[t] = ex;
        }
        __syncthreads();
        for (int i = t; i < cnt; i += NTHR) {
            unsigned int e = sm.b.raw[i];
            int d = e & 127;
            int p = atomicAdd(&sm.b.cursor[d], 1);
            eb[p] = e >> 7;
        }
        if (t < nn) {
            int dg  = sm.b.hist[t];
            int pdg = (dg + 7) & ~7;
            int base = sm.b.startx[t];
            for (int k = dg; k < pdg; ++k) eb[base + k] = (unsigned)dummyIdx;
            int gbase = bucket * CAP_OUT + base;
            rowbeg[node0 + t] = gbase;
            rowend[node0 + t] = gbase + pdg;
            dinv[node0 + t]   = rsqrtf((float)(dg + 1));
        }
    }
    gsync(bcnt, bgen);

    // ---- P3: h' = (x @ W) * dinv via bf16 MFMA ---------------------------
    {
        int m = lane & 15, quad = lane >> 4;
        bf16x8 bfrag[2][4];
#pragma unroll
        for (int c = 0; c < 2; ++c)
#pragma unroll
            for (int nt = 0; nt < 4; ++nt) {
                bf16x8 f;
#pragma unroll
                for (int j = 0; j < 8; ++j) {
                    int k = c * 32 + quad * 8 + j;
                    f[j] = (__bf16)W[k * DIM + nt * 16 + m];
                }
                bfrag[c][nt] = f;
            }
        for (int chunk = gwave; chunk < NCHUNK; chunk += NBLK * 4) {
            int row0 = chunk * 16;
            const float* xr = x + (size_t)(row0 + m) * DIM;
            bf16x8 afrag[2];
#pragma unroll
            for (int c = 0; c < 2; ++c) {
                float4 lo = *(const float4*)(xr + c * 32 + quad * 8);
                float4 hi = *(const float4*)(xr + c * 32 + quad * 8 + 4);
                bf16x8 f;
                f[0] = (__bf16)lo.x; f[1] = (__bf16)lo.y; f[2] = (__bf16)lo.z; f[3] = (__bf16)lo.w;
                f[4] = (__bf16)hi.x; f[5] = (__bf16)hi.y; f[6] = (__bf16)hi.z; f[7] = (__bf16)hi.w;
                afrag[c] = f;
            }
            float dv[4];
#pragma unroll
            for (int r = 0; r < 4; ++r) dv[r] = dinv[row0 + quad * 4 + r];
#pragma unroll
            for (int nt = 0; nt < 4; ++nt) {
                floatx4 acc = {0.f, 0.f, 0.f, 0.f};
                acc = __builtin_amdgcn_mfma_f32_16x16x32_bf16(afrag[0], bfrag[0][nt], acc, 0, 0, 0);
                acc = __builtin_amdgcn_mfma_f32_16x16x32_bf16(afrag[1], bfrag[1][nt], acc, 0, 0, 0);
#pragma unroll
                for (int r = 0; r < 4; ++r) {
                    int row = row0 + quad * 4 + r;
                    hb[(size_t)row * DIM + nt * 16 + m] = f2bf(acc[r] * dv[r]);
                }
            }
        }
    }
    gsync(bcnt, bgen);

    // ---- P4: gather (4 nodes/wave, chunk-aligned routing) + BN partials --
    float s_sum = 0.f, s_sq = 0.f;
    for (int g = gwave; g < NGROUP; g += NBLK * 4) {
        int n0 = g << 2;
        int beg = __builtin_amdgcn_readfirstlane(rowbeg[n0]);
        int s1  = __builtin_amdgcn_readfirstlane(rowbeg[n0 + 1]);
        int s2  = __builtin_amdgcn_readfirstlane(rowbeg[n0 + 2]);
        int s3  = __builtin_amdgcn_readfirstlane(rowbeg[n0 + 3]);
        int end = __builtin_amdgcn_readfirstlane(rowend[n0 + 3]);
        float acc0 = 0.f, acc1 = 0.f, acc2 = 0.f, acc3 = 0.f;
        for (int base = beg; base < end; base += 64) {
            int idx = base + lane;
            unsigned int sv = (idx < end) ? entries[idx] : 0u;
            int cn = min(64, end - base);               // multiple of 8
            for (int j = 0; j < cn; j += 8) {
                int p0 = base + j;                      // wave-uniform
                int k = (p0 >= s1) + (p0 >= s2) + (p0 >= s3);
                float v[8];
#pragma unroll
                for (int u = 0; u < 8; ++u) {
                    unsigned int s = (unsigned)__shfl((int)sv, j + u, 64);
                    v[u] = bf2f(hb[(size_t)s * DIM + lane]);
                }
                float csum = ((v[0] + v[1]) + (v[2] + v[3])) +
                             ((v[4] + v[5]) + (v[6] + v[7]));
                acc0 += (k == 0) ? csum : 0.f;
                acc1 += (k == 1) ? csum : 0.f;
                acc2 += (k == 2) ? csum : 0.f;
                acc3 += (k == 3) ? csum : 0.f;
            }
        }
        float v0 = (acc0 + bf2f(hb[(size_t)(n0 + 0) * DIM + lane])) * dinv[n0 + 0];
        float v1 = (acc1 + bf2f(hb[(size_t)(n0 + 1) * DIM + lane])) * dinv[n0 + 1];
        float v2 = (acc2 + bf2f(hb[(size_t)(n0 + 2) * DIM + lane])) * dinv[n0 + 2];
        float v3 = (acc3 + bf2f(hb[(size_t)(n0 + 3) * DIM + lane])) * dinv[n0 + 3];
        out[(size_t)(n0 + 0) * DIM + lane] = v0;
        out[(size_t)(n0 + 1) * DIM + lane] = v1;
        out[(size_t)(n0 + 2) * DIM + lane] = v2;
        out[(size_t)(n0 + 3) * DIM + lane] = v3;
        s_sum += ((v0 + v1) + (v2 + v3));
        s_sq  += ((v0 * v0 + v1 * v1) + (v2 * v2 + v3 * v3));
    }
    __syncthreads();
    sm.g.red[0][wv][lane] = s_sum;
    sm.g.red[1][wv][lane] = s_sq;
    __syncthreads();
    if (t < 64) {
        partial[(size_t)blk * 128 + t] =
            sm.g.red[0][0][t] + sm.g.red[0][1][t] + sm.g.red[0][2][t] + sm.g.red[0][3][t];
        partial[(size_t)blk * 128 + 64 + t] =
            sm.g.red[1][0][t] + sm.g.red[1][1][t] + sm.g.red[1][2][t] + sm.g.red[1][3][t];
    }
    gsync(bcnt, bgen);

    // ---- P5: fold 1024 partial rows into gsum/gsumsq (blocks 0..63) ------
    if (blk < 64) {
        int col = t & 127;
        int which = t >> 7;
        float acc = 0.f;
        for (int r = blk * 16 + which; r < blk * 16 + 16; r += 2)
            acc += partial[(size_t)r * 128 + col];
        __syncthreads();
        sm.flat[t] = acc;
        __syncthreads();
        if (t < 128) {
            float v = sm.flat[t] + sm.flat[t + 128];
            atomicAdd((t < 64) ? &gsum[t] : &gsumsq[t - 64], v);
        }
    }
    gsync(bcnt, bgen);

    // ---- P6: BN finalize (locally per block) + apply + ReLU --------------
    if (t < 64) {
        float invN = 1.0f / (float)N_NODES;
        float mean = gsum[t] * invN;
        float var  = gsumsq[t] * invN - mean * mean;
        float sc   = gamma[t] * rsqrtf(var + BN_EPS);
        sm.f.scale[t] = sc;
        sm.f.shift[t] = beta[t] - mean * sc;
    }
    __syncthreads();
    {
        float4* o4 = (float4*)out;
        const int total4 = N_NODES * DIM / 4;
        for (int i = blk * NTHR + t; i < total4; i += NBLK * NTHR) {
            int c = (i * 4) & 63;
            float4 v = o4[i];
            float a0 = fmaf(v.x, sm.f.scale[c],     sm.f.shift[c]);
            float a1 = fmaf(v.y, sm.f.scale[c + 1], sm.f.shift[c + 1]);
            float a2 = fmaf(v.z, sm.f.scale[c + 2], sm.f.shift[c + 2]);
            float a3 = fmaf(v.w, sm.f.scale[c + 3], sm.f.shift[c + 3]);
            v.x = a0 > 0.f ? a0 : 0.f;
            v.y = a1 > 0.f ? a1 : 0.f;
            v.z = a2 > 0.f ? a2 : 0.f;
            v.w = a3 > 0.f ? a3 : 0.f;
            o4[i] = v;
        }
    }
}

extern "C" void kernel_launch(void* const* d_in, const int* in_sizes, int n_in,
                              void* d_out, int out_size, void* d_ws, size_t ws_size,
                              hipStream_t stream) {
    const float* x     = (const float*)d_in[0];          // [N, 64]
    const int*   eidx  = (const int*)d_in[1];            // [2, E]
    const float* W     = (const float*)d_in[2];          // [64, 64]
    // d_in[3] = b : cancels in BatchNorm (uniform per-column shift)
    const float* gamma = (const float*)d_in[4];          // [64]
    const float* beta  = (const float*)d_in[5];          // [64]
    float* out = (float*)d_out;                          // [N, 64]

    const int* src = eidx;
    const int* dst = eidx + N_EDGES;

    // workspace layout (byte offsets; all multiples of 128)
    char* ws = (char*)d_ws;
    size_t off_hb      = 0;                                   // N*DIM*2 = 12,800,000
    size_t off_dinv    = off_hb + (size_t)N_NODES * DIM * 2;  // 12,800,000
    size_t off_rowbeg  = off_dinv + (size_t)N_NODES * 4;      // 13,200,000
    size_t off_rowend  = off_rowbeg + (size_t)N_NODES * 4;    // 13,600,000
    size_t off_entries = off_rowend + (size_t)N_NODES * 4;    // 14,000,000
    size_t off_partial = off_entries + (size_t)NBUCK * CAP_OUT * 4;  // 25,210,752
    size_t off_z       = off_partial + (size_t)NBLK * 128 * 4;       // 25,735,040

    unsigned short* hb = (unsigned short*)(ws + off_hb);
    float* dinv        = (float*)(ws + off_dinv);
    int*   rowbeg      = (int*)(ws + off_rowbeg);
    int*   rowend      = (int*)(ws + off_rowend);
    unsigned int* entries = (unsigned int*)(ws + off_entries);
    float* partial     = (float*)(ws + off_partial);
    // zero region: dummy hb row [128 B] | cur[NBUCK] | bcnt | bgen | gsum[64] | gsumsq[64]
    int*   cur   = (int*)(ws + off_z + 128);
    int*   bcnt  = cur + NBUCK;
    int*   bgen  = bcnt + 1;
    float* gsum  = (float*)(bgen + 1);
    float* gsumsq = gsum + 64;
    int dummyIdx = (int)(off_z / (DIM * 2));             // hb row index of the zero block

    size_t zbytes = 128 + (size_t)NBUCK * 4 + 8 + 512;   // 3776 B
    hipMemsetAsync(ws + off_z, 0, zbytes, stream);

    fused_kernel<<<NBLK, NTHR, 0, stream>>>(src, dst, x, W, gamma, beta, out,
                                            hb, dinv, rowbeg, rowend, entries, partial,
                                            cur, bcnt, bgen, gsum, gsumsq, dummyIdx);
}

// Round 12
// 197.727 us; speedup vs baseline: 6.6131x; 6.6131x over previous
//
#include <hip/hip_runtime.h>

#define N_NODES 100000
#define N_EDGES 1600000
#define DIM 64
#define BN_EPS 1e-5f

#define BNODES 128                        // nodes per bucket (7 bits)
#define NBUCK ((N_NODES + BNODES - 1) / BNODES)  // 782
#define CAP_RAW 2560                      // raw entries/bucket: mean 2046, +11 sigma
#define CAP_OUT 3584                      // sorted+padded capacity
#define TILE 4096                         // edges per passA block
#define ABLK ((N_EDGES + TILE - 1) / TILE)  // 391

#define GBLK 6250                         // gather blocks (4 waves x 4 nodes each)

typedef __bf16 bf16x8 __attribute__((ext_vector_type(8)));
typedef float floatx4 __attribute__((ext_vector_type(4)));

// ---- bf16 helpers (manual RNE) -------------------------------------------
static __device__ __forceinline__ unsigned short f2bf(float f) {
    unsigned u = __float_as_uint(f);
    u = (u + 0x7FFFu + ((u >> 16) & 1u)) >> 16;
    return (unsigned short)u;
}
static __device__ __forceinline__ float bf2f(unsigned short h) {
    return __uint_as_float(((unsigned)h) << 16);
}

// ---------------- passA: coarse partition into 128-node buckets -----------
// 391 blocks x 16 waves (~24 waves/CU); 4 edges/thread in registers across
// both phases; staggered bucket reservation de-bursts same-line atomics.
__global__ void __launch_bounds__(1024)
passA_kernel(const int* __restrict__ src, const int* __restrict__ dst,
             int* __restrict__ cur, unsigned int* __restrict__ entries, int E) {
    __shared__ int hist[NBUCK];
    __shared__ int lbase[NBUCK];
    int t = threadIdx.x;
    if (t < NBUCK) hist[t] = 0;
    __syncthreads();

    int e0   = blockIdx.x * TILE;
    int eend = min(e0 + TILE, E);

    int dreg[4], sreg[4], ne = 0;
    for (int e = e0 + t; e < eend; e += 1024) {
        dreg[ne] = dst[e];
        sreg[ne] = src[e];
        atomicAdd(&hist[dreg[ne] >> 7], 1);
        ++ne;
    }
    __syncthreads();
    if (t < NBUCK) {
        int ii = t + (blockIdx.x * 331) % NBUCK;   // staggered start
        if (ii >= NBUCK) ii -= NBUCK;
        int c = hist[ii];
        lbase[ii] = (c > 0) ? atomicAdd(&cur[ii], c) : 0;
        hist[ii] = 0;                      // reuse as local cursor
    }
    __syncthreads();
    for (int k = 0; k < ne; ++k) {
        int s = sreg[k];
        int d = dreg[k];
        int b = d >> 7;
        int r = atomicAdd(&hist[b], 1);
        int pos = lbase[b] + r;
        if (pos < CAP_RAW)                // safety valve; statistically never
            entries[(size_t)b * CAP_OUT + pos] = ((unsigned)s << 7) | (unsigned)(d & 127);
    }
}

// ---------------- build: in-LDS counting sort + MFMA GEMM (fused) ---------
// Bucket b's nodes ARE rows [128b, 128b+128): after the sort yields exact
// degrees, the same block runs the bf16 MFMA GEMM for its own rows using
// LDS-resident dinv — zero cross-block dependency, one launch saved.
__global__ void __launch_bounds__(256)
build_kernel(unsigned int* __restrict__ entries, const int* __restrict__ cur,
             int* __restrict__ rowbeg, int* __restrict__ rowend,
             float* __restrict__ dinv,
             const float* __restrict__ x, const float* __restrict__ W,
             unsigned short* __restrict__ hb, int dummyIdx, int N) {
    __shared__ unsigned int raw[CAP_RAW]; // 10 KB
    __shared__ int hist[BNODES];
    __shared__ int sbuf[BNODES];
    __shared__ int startx[BNODES];
    __shared__ int cursor[BNODES];
    __shared__ float sdinv[BNODES];
    int bucket = blockIdx.x;
    int t = threadIdx.x;                  // 256 threads = 4 waves
    int node0 = bucket * BNODES;
    int nn = min(BNODES, N - node0);
    int cnt = min(cur[bucket], CAP_RAW);
    unsigned int* eb = entries + (size_t)bucket * CAP_OUT;

    if (t < BNODES) hist[t] = 0;
    __syncthreads();
    for (int i = t; i < cnt; i += 256) {
        unsigned int e = eb[i];
        raw[i] = e;
        atomicAdd(&hist[e & 127], 1);
    }
    __syncthreads();
    int pdeg_t = 0;
    if (t < BNODES) { pdeg_t = (hist[t] + 7) & ~7; sbuf[t] = pdeg_t; }
    __syncthreads();
    for (int off = 1; off < BNODES; off <<= 1) {
        int add = (t < BNODES && t >= off) ? sbuf[t - off] : 0;
        __syncthreads();
        if (t < BNODES) sbuf[t] += add;
        __syncthreads();
    }
    if (t < BNODES) {
        int ex = sbuf[t] - pdeg_t;        // exclusive padded scan
        startx[t] = ex;
        cursor[t] = ex;
    }
    __syncthreads();
    for (int i = t; i < cnt; i += 256) {
        unsigned int e = raw[i];
        int d = e & 127;
        int p = atomicAdd(&cursor[d], 1);
        eb[p] = e >> 7;                   // store src only
    }
    if (t < nn) {
        int dg  = hist[t];                // exact degree of this node
        int pdg = (dg + 7) & ~7;
        int base = startx[t];
        for (int k = dg; k < pdg; ++k) eb[base + k] = (unsigned)dummyIdx;
        int gbase = bucket * CAP_OUT + base;
        rowbeg[node0 + t] = gbase;
        rowend[node0 + t] = gbase + pdg;
        float di = rsqrtf((float)(dg + 1));  // self-loop included
        dinv[node0 + t] = di;
        sdinv[t] = di;
    }
    __syncthreads();

    // ---- GEMM phase: rows node0 .. node0+nn (nn is a multiple of 16) -----
    int lane = t & 63, wv = t >> 6;
    int m = lane & 15, quad = lane >> 4;
    int nchunk = nn >> 4;                 // 8 (last bucket: 2)
    if (wv < nchunk || nchunk == 8) {     // cheap guard; full buckets all work
        bf16x8 bfrag[2][4];
#pragma unroll
        for (int c = 0; c < 2; ++c)
#pragma unroll
            for (int nt = 0; nt < 4; ++nt) {
                bf16x8 f;
#pragma unroll
                for (int j = 0; j < 8; ++j) {
                    int k = c * 32 + quad * 8 + j;
                    f[j] = (__bf16)W[k * DIM + nt * 16 + m];
                }
                bfrag[c][nt] = f;
            }
        for (int c2 = wv; c2 < nchunk; c2 += 4) {
            int lrow0 = c2 * 16;
            int row0 = node0 + lrow0;
            const float* xr = x + (size_t)(row0 + m) * DIM;
            bf16x8 afrag[2];
#pragma unroll
            for (int c = 0; c < 2; ++c) {
                float4 lo = *(const float4*)(xr + c * 32 + quad * 8);
                float4 hi = *(const float4*)(xr + c * 32 + quad * 8 + 4);
                bf16x8 f;
                f[0] = (__bf16)lo.x; f[1] = (__bf16)lo.y; f[2] = (__bf16)lo.z; f[3] = (__bf16)lo.w;
                f[4] = (__bf16)hi.x; f[5] = (__bf16)hi.y; f[6] = (__bf16)hi.z; f[7] = (__bf16)hi.w;
                afrag[c] = f;
            }
            float dv[4];
#pragma unroll
            for (int r = 0; r < 4; ++r) dv[r] = sdinv[lrow0 + quad * 4 + r];
#pragma unroll
            for (int nt = 0; nt < 4; ++nt) {
                floatx4 acc = {0.f, 0.f, 0.f, 0.f};
                acc = __builtin_amdgcn_mfma_f32_16x16x32_bf16(afrag[0], bfrag[0][nt], acc, 0, 0, 0);
                acc = __builtin_amdgcn_mfma_f32_16x16x32_bf16(afrag[1], bfrag[1][nt], acc, 0, 0, 0);
#pragma unroll
                for (int r = 0; r < 4; ++r) {
                    int row = row0 + quad * 4 + r;
                    hb[(size_t)row * DIM + nt * 16 + m] = f2bf(acc[r] * dv[r]);
                }
            }
        }
    }
}

// ---------------- gather: 4 nodes/wave, chunk-aligned routing -------------
__global__ void __launch_bounds__(256)
gather_kernel(const int* __restrict__ rowbeg, const int* __restrict__ rowend,
              const unsigned int* __restrict__ srt, const unsigned short* __restrict__ hb,
              const float* __restrict__ dinv, float* __restrict__ out,
              float* __restrict__ partial, int N) {
    __shared__ float red[2][4][64];
    int lane = threadIdx.x & 63;
    int wv   = threadIdx.x >> 6;
    int g    = blockIdx.x * 4 + wv;
    int n0   = g << 2;
    float s_sum = 0.f, s_sq = 0.f;

    if (n0 < N) {  // uniform per wave; N % 4 == 0; groups never straddle buckets
        int beg = __builtin_amdgcn_readfirstlane(rowbeg[n0]);
        int s1  = __builtin_amdgcn_readfirstlane(rowbeg[n0 + 1]);
        int s2  = __builtin_amdgcn_readfirstlane(rowbeg[n0 + 2]);
        int s3  = __builtin_amdgcn_readfirstlane(rowbeg[n0 + 3]);
        int end = __builtin_amdgcn_readfirstlane(rowend[n0 + 3]);
        float acc0 = 0.f, acc1 = 0.f, acc2 = 0.f, acc3 = 0.f;

        for (int base = beg; base < end; base += 64) {
            int idx = base + lane;
            unsigned int sv = (idx < end) ? srt[idx] : 0u;  // coalesced batch
            int cn = min(64, end - base);                   // multiple of 8
            for (int j = 0; j < cn; j += 8) {
                int p0 = base + j;                          // uniform (SALU)
                int k = (p0 >= s1) + (p0 >= s2) + (p0 >= s3);
                float v[8];
#pragma unroll
                for (int u = 0; u < 8; ++u) {
                    unsigned int s = (unsigned)__shfl((int)sv, j + u, 64);
                    v[u] = bf2f(hb[(size_t)s * DIM + lane]);
                }
                float csum = ((v[0] + v[1]) + (v[2] + v[3])) +
                             ((v[4] + v[5]) + (v[6] + v[7]));
                acc0 += (k == 0) ? csum : 0.f;
                acc1 += (k == 1) ? csum : 0.f;
                acc2 += (k == 2) ? csum : 0.f;
                acc3 += (k == 3) ? csum : 0.f;
            }
        }

        float v0 = (acc0 + bf2f(hb[(size_t)(n0 + 0) * DIM + lane])) * dinv[n0 + 0];
        float v1 = (acc1 + bf2f(hb[(size_t)(n0 + 1) * DIM + lane])) * dinv[n0 + 1];
        float v2 = (acc2 + bf2f(hb[(size_t)(n0 + 2) * DIM + lane])) * dinv[n0 + 2];
        float v3 = (acc3 + bf2f(hb[(size_t)(n0 + 3) * DIM + lane])) * dinv[n0 + 3];
        out[(size_t)(n0 + 0) * DIM + lane] = v0;
        out[(size_t)(n0 + 1) * DIM + lane] = v1;
        out[(size_t)(n0 + 2) * DIM + lane] = v2;
        out[(size_t)(n0 + 3) * DIM + lane] = v3;
        s_sum = ((v0 + v1) + (v2 + v3));
        s_sq  = ((v0 * v0 + v1 * v1) + (v2 * v2 + v3 * v3));
    }

    red[0][wv][lane] = s_sum;
    red[1][wv][lane] = s_sq;
    __syncthreads();
    if (threadIdx.x < 64) {
        int c = threadIdx.x;
        partial[(size_t)blockIdx.x * 128 + c] =
            red[0][0][c] + red[0][1][c] + red[0][2][c] + red[0][3][c];
        partial[(size_t)blockIdx.x * 128 + 64 + c] =
            red[1][0][c] + red[1][1][c] + red[1][2][c] + red[1][3][c];
    }
}

// ---------------- reduce2: fold per-block BN partials ---------------------
__global__ void reduce2_kernel(const float* __restrict__ partial, float* __restrict__ gstat) {
    __shared__ float buf[256];
    int t = threadIdx.x;
    int col = t & 127;
    int half = t >> 7;                    // 0 or 1
    int r0 = blockIdx.x * 125;            // 50 blocks x 125 rows = 6250
    float acc = 0.f;
    for (int r = r0 + half; r < r0 + 125; r += 2)
        acc += partial[(size_t)r * 128 + col];
    buf[t] = acc;
    __syncthreads();
    if (t < 128) atomicAdd(&gstat[t], buf[t] + buf[t + 128]);  // gsum[64]|gsumsq[64]
}

// ---------------- finish: BN finalize (per block) + apply + ReLU ----------
// bias b cancels in BN (uniform per-column shift), so it's omitted entirely.
__global__ void __launch_bounds__(256)
finish_kernel(float4* __restrict__ out, const float* __restrict__ gstat,
              const float* __restrict__ gamma, const float* __restrict__ beta,
              int total4, int N) {
    __shared__ float scale[64];
    __shared__ float shift[64];
    int t = threadIdx.x;
    if (t < 64) {
        float invN = 1.0f / (float)N;
        float mean = gstat[t] * invN;
        float var  = gstat[64 + t] * invN - mean * mean;
        float sc   = gamma[t] * rsqrtf(var + BN_EPS);
        scale[t] = sc;
        shift[t] = beta[t] - mean * sc;
    }
    __syncthreads();
    int i = blockIdx.x * blockDim.x + t;
    if (i >= total4) return;
    int c = (i * 4) & 63;
    float4 v = out[i];
    float a0 = fmaf(v.x, scale[c],     shift[c]);
    float a1 = fmaf(v.y, scale[c + 1], shift[c + 1]);
    float a2 = fmaf(v.z, scale[c + 2], shift[c + 2]);
    float a3 = fmaf(v.w, scale[c + 3], shift[c + 3]);
    v.x = a0 > 0.f ? a0 : 0.f;
    v.y = a1 > 0.f ? a1 : 0.f;
    v.z = a2 > 0.f ? a2 : 0.f;
    v.w = a3 > 0.f ? a3 : 0.f;
    out[i] = v;
}

extern "C" void kernel_launch(void* const* d_in, const int* in_sizes, int n_in,
                              void* d_out, int out_size, void* d_ws, size_t ws_size,
                              hipStream_t stream) {
    const float* x     = (const float*)d_in[0];          // [N, 64]
    const int*   eidx  = (const int*)d_in[1];            // [2, E]
    const float* W     = (const float*)d_in[2];          // [64, 64]
    // d_in[3] = b : cancels in BatchNorm (uniform per-column shift)
    const float* gamma = (const float*)d_in[4];          // [64]
    const float* beta  = (const float*)d_in[5];          // [64]
    float* out = (float*)d_out;                          // [N, 64]

    const int N = N_NODES;
    const int total = N * DIM;

    const int* src = eidx;
    const int* dst = eidx + N_EDGES;

    // workspace layout (byte offsets; hb rows are 128 B)
    char* ws = (char*)d_ws;
    size_t off_hb      = 0;                                   // N*128 = 12,800,000
    size_t off_dinv    = off_hb + (size_t)N * DIM * 2;        // 12,800,000
    size_t off_rowbeg  = off_dinv + (size_t)N * 4;            // 13,200,000
    size_t off_rowend  = off_rowbeg + (size_t)N * 4;          // 13,600,000
    size_t off_entries = off_rowend + (size_t)N * 4;          // 14,000,000
    size_t off_partial = off_entries + (size_t)NBUCK * CAP_OUT * 4;  // 25,210,752
    size_t off_z       = off_partial + (size_t)GBLK * 128 * 4;       // 28,410,752 (mult of 128)

    unsigned short* hb    = (unsigned short*)(ws + off_hb);
    float*          dinv  = (float*)(ws + off_dinv);
    int*            rowbeg = (int*)(ws + off_rowbeg);
    int*            rowend = (int*)(ws + off_rowend);
    unsigned int*   entries = (unsigned int*)(ws + off_entries);
    float*          partial = (float*)(ws + off_partial);
    // zero region: dummy hb row [128 B] | cur[NBUCK] | gstat[128]
    int*   cur   = (int*)(ws + off_z + 128);
    float* gstat = (float*)(cur + NBUCK);
    int dummyIdx = (int)(off_z / (DIM * 2));             // hb row index of zero block

    size_t zbytes = 128 + (size_t)NBUCK * 4 + 512;       // 3768 B
    hipMemsetAsync(ws + off_z, 0, zbytes, stream);

    passA_kernel<<<ABLK, 1024, 0, stream>>>(src, dst, cur, entries, N_EDGES);

    build_kernel<<<NBUCK, 256, 0, stream>>>(entries, cur, rowbeg, rowend, dinv,
                                            x, W, hb, dummyIdx, N);

    gather_kernel<<<GBLK, 256, 0, stream>>>(rowbeg, rowend, entries, hb, dinv, out, partial, N);

    reduce2_kernel<<<50, 256, 0, stream>>>(partial, gstat);

    finish_kernel<<<(total / 4 + 255) / 256, 256, 0, stream>>>((float4*)out, gstat,
                                                               gamma, beta, total / 4, N);
}

// Round 13
// 194.133 us; speedup vs baseline: 6.7355x; 1.0185x over previous
//
#include <hip/hip_runtime.h>

#define N_NODES 100000
#define N_EDGES 1600000
#define DIM 64
#define BN_EPS 1e-5f

#define BNODES 128                        // nodes per bucket (7 bits)
#define NBUCK ((N_NODES + BNODES - 1) / BNODES)  // 782
#define CAP_RAW 2560                      // raw entries/bucket: mean 2046, +11 sigma
#define CAP_OUT 3584                      // sorted+padded capacity
#define TILE 4096                         // edges per passA block
#define ABLK ((N_EDGES + TILE - 1) / TILE)  // 391

#define GBLK 6250                         // gather blocks (4 waves x 4 nodes each)

typedef __bf16 bf16x8 __attribute__((ext_vector_type(8)));
typedef float floatx4 __attribute__((ext_vector_type(4)));

// ---- bf16 helpers (manual RNE) -------------------------------------------
static __device__ __forceinline__ unsigned short f2bf(float f) {
    unsigned u = __float_as_uint(f);
    u = (u + 0x7FFFu + ((u >> 16) & 1u)) >> 16;
    return (unsigned short)u;
}
static __device__ __forceinline__ float bf2f(unsigned short h) {
    return __uint_as_float(((unsigned)h) << 16);
}

// ---------------- passA: coarse partition into 128-node buckets -----------
// int4 loads: thread t owns edges [e0+4t, e0+4t+4) — one dwordx4 each for
// src and dst; staggered bucket reservation de-bursts same-line atomics.
__global__ void __launch_bounds__(1024)
passA_kernel(const int* __restrict__ src, const int* __restrict__ dst,
             int* __restrict__ cur, unsigned int* __restrict__ entries, int E) {
    __shared__ int hist[NBUCK];
    __shared__ int lbase[NBUCK];
    int t = threadIdx.x;
    if (t < NBUCK) hist[t] = 0;
    __syncthreads();

    int e0   = blockIdx.x * TILE;
    int eend = min(e0 + TILE, E);
    int eb   = e0 + t * 4;

    int dreg[4], sreg[4], ne = 0;
    if (eb + 3 < eend) {
        int4 d4 = *(const int4*)(dst + eb);
        int4 s4 = *(const int4*)(src + eb);
        dreg[0] = d4.x; dreg[1] = d4.y; dreg[2] = d4.z; dreg[3] = d4.w;
        sreg[0] = s4.x; sreg[1] = s4.y; sreg[2] = s4.z; sreg[3] = s4.w;
        ne = 4;
    } else {
        for (int e = eb; e < eend && ne < 4; ++e, ++ne) {
            dreg[ne] = dst[e];
            sreg[ne] = src[e];
        }
    }
#pragma unroll
    for (int k = 0; k < 4; ++k)
        if (k < ne) atomicAdd(&hist[dreg[k] >> 7], 1);
    __syncthreads();
    if (t < NBUCK) {
        int ii = t + (blockIdx.x * 331) % NBUCK;   // staggered start
        if (ii >= NBUCK) ii -= NBUCK;
        int c = hist[ii];
        lbase[ii] = (c > 0) ? atomicAdd(&cur[ii], c) : 0;
        hist[ii] = 0;                      // reuse as local cursor
    }
    __syncthreads();
#pragma unroll
    for (int k = 0; k < 4; ++k) {
        if (k >= ne) break;
        int s = sreg[k];
        int d = dreg[k];
        int b = d >> 7;
        int r = atomicAdd(&hist[b], 1);
        int pos = lbase[b] + r;
        if (pos < CAP_RAW)                // safety valve; statistically never
            entries[(size_t)b * CAP_OUT + pos] = ((unsigned)s << 7) | (unsigned)(d & 127);
    }
}

// ---------------- build: counting sort (node,src-quarter) + MFMA GEMM -----
// Sub-sort key = node*4 + src/25000: gather then reads hb one ~3.2 MB
// quarter at a time -> per-XCD L2-resident working set. Node segments stay
// 8-padded (pad appended at node end), so chunk routing is unchanged.
// GEMM is operand-swapped (D = W^T·x^T tile): each lane's 4 acc regs are
// 4 consecutive features of ONE row -> single ushort4 store per nt.
__global__ void __launch_bounds__(256)
build_kernel(unsigned int* __restrict__ entries, const int* __restrict__ cur,
             int* __restrict__ rowbeg, int* __restrict__ rowend,
             float* __restrict__ dinv,
             const float* __restrict__ x, const float* __restrict__ W,
             unsigned short* __restrict__ hb, int dummyIdx, int N) {
    __shared__ unsigned int raw[CAP_RAW]; // 10 KB
    __shared__ int hist[BNODES * 4];      // per (node,quarter) counts
    __shared__ int sbuf[BNODES];
    __shared__ int nstart[BNODES];
    __shared__ int cursor[BNODES * 4];
    __shared__ float sdinv[BNODES];
    int bucket = blockIdx.x;
    int t = threadIdx.x;                  // 256 threads = 4 waves
    int node0 = bucket * BNODES;
    int nn = min(BNODES, N - node0);
    int cnt = min(cur[bucket], CAP_RAW);
    unsigned int* eb = entries + (size_t)bucket * CAP_OUT;

    for (int i = t; i < BNODES * 4; i += 256) hist[i] = 0;
    __syncthreads();
    for (int i = t; i < cnt; i += 256) {
        unsigned int e = eb[i];
        raw[i] = e;
        int s = (int)(e >> 7);
        int q = (s >= 25000) + (s >= 50000) + (s >= 75000);
        atomicAdd(&hist[((e & 127) << 2) | q], 1);
    }
    __syncthreads();
    int deg_t = 0, pdeg_t = 0;
    if (t < BNODES) {
        deg_t = hist[t * 4] + hist[t * 4 + 1] + hist[t * 4 + 2] + hist[t * 4 + 3];
        pdeg_t = (deg_t + 7) & ~7;
        sbuf[t] = pdeg_t;
    }
    __syncthreads();
    for (int off = 1; off < BNODES; off <<= 1) {
        int add = (t < BNODES && t >= off) ? sbuf[t - off] : 0;
        __syncthreads();
        if (t < BNODES) sbuf[t] += add;
        __syncthreads();
    }
    if (t < BNODES) {
        int ex = sbuf[t] - pdeg_t;        // exclusive padded node start
        nstart[t] = ex;
        int o = ex;
        cursor[t * 4 + 0] = o; o += hist[t * 4 + 0];
        cursor[t * 4 + 1] = o; o += hist[t * 4 + 1];
        cursor[t * 4 + 2] = o; o += hist[t * 4 + 2];
        cursor[t * 4 + 3] = o;
    }
    __syncthreads();
    for (int i = t; i < cnt; i += 256) {
        unsigned int e = raw[i];
        int s = (int)(e >> 7);
        int q = (s >= 25000) + (s >= 50000) + (s >= 75000);
        int p = atomicAdd(&cursor[((e & 127) << 2) | q], 1);
        eb[p] = (unsigned)s;              // store src only, quarter-sorted
    }
    if (t < nn) {
        int dg  = deg_t;
        int pdg = pdeg_t;
        int base = nstart[t];
        for (int k = dg; k < pdg; ++k) eb[base + k] = (unsigned)dummyIdx;
        int gbase = bucket * CAP_OUT + base;
        rowbeg[node0 + t] = gbase;
        rowend[node0 + t] = gbase + pdg;
        float di = rsqrtf((float)(dg + 1));  // self-loop included
        dinv[node0 + t] = di;
        sdinv[t] = di;
    }
    __syncthreads();

    // ---- GEMM phase: rows node0 .. node0+nn (nn is a multiple of 16) -----
    int lane = t & 63, wv = t >> 6;
    int m = lane & 15, quad = lane >> 4;
    int nchunk = nn >> 4;                 // 8 (last bucket: 2)
    bf16x8 bfrag[2][4];
#pragma unroll
    for (int c = 0; c < 2; ++c)
#pragma unroll
        for (int nt = 0; nt < 4; ++nt) {
            bf16x8 f;
#pragma unroll
            for (int j = 0; j < 8; ++j) {
                int k = c * 32 + quad * 8 + j;
                f[j] = (__bf16)W[k * DIM + nt * 16 + m];
            }
            bfrag[c][nt] = f;
        }
    for (int c2 = wv; c2 < nchunk; c2 += 4) {
        int lrow0 = c2 * 16;
        int row0 = node0 + lrow0;
        const float* xr = x + (size_t)(row0 + m) * DIM;
        bf16x8 afrag[2];
#pragma unroll
        for (int c = 0; c < 2; ++c) {
            float4 lo = *(const float4*)(xr + c * 32 + quad * 8);
            float4 hi = *(const float4*)(xr + c * 32 + quad * 8 + 4);
            bf16x8 f;
            f[0] = (__bf16)lo.x; f[1] = (__bf16)lo.y; f[2] = (__bf16)lo.z; f[3] = (__bf16)lo.w;
            f[4] = (__bf16)hi.x; f[5] = (__bf16)hi.y; f[6] = (__bf16)hi.z; f[7] = (__bf16)hi.w;
            afrag[c] = f;
        }
        float dv = sdinv[lrow0 + m];      // one dinv per lane (its row)
#pragma unroll
        for (int nt = 0; nt < 4; ++nt) {
            floatx4 acc = {0.f, 0.f, 0.f, 0.f};
            // operand-swapped: D[feature][xrow] -> lane m = xrow, regs = 4
            // consecutive features nt*16+quad*4+r
            acc = __builtin_amdgcn_mfma_f32_16x16x32_bf16(bfrag[0][nt], afrag[0], acc, 0, 0, 0);
            acc = __builtin_amdgcn_mfma_f32_16x16x32_bf16(bfrag[1][nt], afrag[1], acc, 0, 0, 0);
            ushort4 pk;
            pk.x = f2bf(acc[0] * dv);
            pk.y = f2bf(acc[1] * dv);
            pk.z = f2bf(acc[2] * dv);
            pk.w = f2bf(acc[3] * dv);
            *(ushort4*)(hb + (size_t)(row0 + m) * DIM + nt * 16 + quad * 4) = pk;
        }
    }
}

// ---------------- gather: 4 nodes/wave, chunk-aligned routing -------------
__global__ void __launch_bounds__(256)
gather_kernel(const int* __restrict__ rowbeg, const int* __restrict__ rowend,
              const unsigned int* __restrict__ srt, const unsigned short* __restrict__ hb,
              const float* __restrict__ dinv, float* __restrict__ out,
              float* __restrict__ partial, int N) {
    __shared__ float red[2][4][64];
    int lane = threadIdx.x & 63;
    int wv   = threadIdx.x >> 6;
    int g    = blockIdx.x * 4 + wv;
    int n0   = g << 2;
    float s_sum = 0.f, s_sq = 0.f;

    if (n0 < N) {  // uniform per wave; N % 4 == 0; groups never straddle buckets
        int beg = __builtin_amdgcn_readfirstlane(rowbeg[n0]);
        int s1  = __builtin_amdgcn_readfirstlane(rowbeg[n0 + 1]);
        int s2  = __builtin_amdgcn_readfirstlane(rowbeg[n0 + 2]);
        int s3  = __builtin_amdgcn_readfirstlane(rowbeg[n0 + 3]);
        int end = __builtin_amdgcn_readfirstlane(rowend[n0 + 3]);
        float acc0 = 0.f, acc1 = 0.f, acc2 = 0.f, acc3 = 0.f;

        for (int base = beg; base < end; base += 64) {
            int idx = base + lane;
            unsigned int sv = (idx < end) ? srt[idx] : 0u;  // coalesced batch
            int cn = min(64, end - base);                   // multiple of 8
            for (int j = 0; j < cn; j += 8) {
                int p0 = base + j;                          // uniform (SALU)
                int k = (p0 >= s1) + (p0 >= s2) + (p0 >= s3);
                float v[8];
#pragma unroll
                for (int u = 0; u < 8; ++u) {
                    // uniform lane index -> readlane -> SGPR base address
                    unsigned int s = (unsigned)__builtin_amdgcn_readlane((int)sv, j + u);
                    v[u] = bf2f(hb[(size_t)s * DIM + lane]);
                }
                float csum = ((v[0] + v[1]) + (v[2] + v[3])) +
                             ((v[4] + v[5]) + (v[6] + v[7]));
                acc0 += (k == 0) ? csum : 0.f;
                acc1 += (k == 1) ? csum : 0.f;
                acc2 += (k == 2) ? csum : 0.f;
                acc3 += (k == 3) ? csum : 0.f;
            }
        }

        float v0 = (acc0 + bf2f(hb[(size_t)(n0 + 0) * DIM + lane])) * dinv[n0 + 0];
        float v1 = (acc1 + bf2f(hb[(size_t)(n0 + 1) * DIM + lane])) * dinv[n0 + 1];
        float v2 = (acc2 + bf2f(hb[(size_t)(n0 + 2) * DIM + lane])) * dinv[n0 + 2];
        float v3 = (acc3 + bf2f(hb[(size_t)(n0 + 3) * DIM + lane])) * dinv[n0 + 3];
        out[(size_t)(n0 + 0) * DIM + lane] = v0;
        out[(size_t)(n0 + 1) * DIM + lane] = v1;
        out[(size_t)(n0 + 2) * DIM + lane] = v2;
        out[(size_t)(n0 + 3) * DIM + lane] = v3;
        s_sum = ((v0 + v1) + (v2 + v3));
        s_sq  = ((v0 * v0 + v1 * v1) + (v2 * v2 + v3 * v3));
    }

    red[0][wv][lane] = s_sum;
    red[1][wv][lane] = s_sq;
    __syncthreads();
    if (threadIdx.x < 64) {
        int c = threadIdx.x;
        partial[(size_t)blockIdx.x * 128 + c] =
            red[0][0][c] + red[0][1][c] + red[0][2][c] + red[0][3][c];
        partial[(size_t)blockIdx.x * 128 + 64 + c] =
            red[1][0][c] + red[1][1][c] + red[1][2][c] + red[1][3][c];
    }
}

// ---------------- reduce2: fold per-block BN partials ---------------------
__global__ void reduce2_kernel(const float* __restrict__ partial, float* __restrict__ gstat) {
    __shared__ float buf[256];
    int t = threadIdx.x;
    int col = t & 127;
    int half = t >> 7;                    // 0 or 1
    int r0 = blockIdx.x * 125;            // 50 blocks x 125 rows = 6250
    float acc = 0.f;
    for (int r = r0 + half; r < r0 + 125; r += 2)
        acc += partial[(size_t)r * 128 + col];
    buf[t] = acc;
    __syncthreads();
    if (t < 128) atomicAdd(&gstat[t], buf[t] + buf[t + 128]);  // gsum[64]|gsumsq[64]
}

// ---------------- finish: BN finalize (per block) + apply + ReLU ----------
// bias b cancels in BN (uniform per-column shift), so it's omitted entirely.
__global__ void __launch_bounds__(256)
finish_kernel(float4* __restrict__ out, const float* __restrict__ gstat,
              const float* __restrict__ gamma, const float* __restrict__ beta,
              int total4, int N) {
    __shared__ float scale[64];
    __shared__ float shift[64];
    int t = threadIdx.x;
    if (t < 64) {
        float invN = 1.0f / (float)N;
        float mean = gstat[t] * invN;
        float var  = gstat[64 + t] * invN - mean * mean;
        float sc   = gamma[t] * rsqrtf(var + BN_EPS);
        scale[t] = sc;
        shift[t] = beta[t] - mean * sc;
    }
    __syncthreads();
    int i = blockIdx.x * blockDim.x + t;
    if (i >= total4) return;
    int c = (i * 4) & 63;
    float4 v = out[i];
    float a0 = fmaf(v.x, scale[c],     shift[c]);
    float a1 = fmaf(v.y, scale[c + 1], shift[c + 1]);
    float a2 = fmaf(v.z, scale[c + 2], shift[c + 2]);
    float a3 = fmaf(v.w, scale[c + 3], shift[c + 3]);
    v.x = a0 > 0.f ? a0 : 0.f;
    v.y = a1 > 0.f ? a1 : 0.f;
    v.z = a2 > 0.f ? a2 : 0.f;
    v.w = a3 > 0.f ? a3 : 0.f;
    out[i] = v;
}

extern "C" void kernel_launch(void* const* d_in, const int* in_sizes, int n_in,
                              void* d_out, int out_size, void* d_ws, size_t ws_size,
                              hipStream_t stream) {
    const float* x     = (const float*)d_in[0];          // [N, 64]
    const int*   eidx  = (const int*)d_in[1];            // [2, E]
    const float* W     = (const float*)d_in[2];          // [64, 64]
    // d_in[3] = b : cancels in BatchNorm (uniform per-column shift)
    const float* gamma = (const float*)d_in[4];          // [64]
    const float* beta  = (const float*)d_in[5];          // [64]
    float* out = (float*)d_out;                          // [N, 64]

    const int N = N_NODES;
    const int total = N * DIM;

    const int* src = eidx;
    const int* dst = eidx + N_EDGES;

    // workspace layout (byte offsets; hb rows are 128 B)
    char* ws = (char*)d_ws;
    size_t off_hb      = 0;                                   // N*128 = 12,800,000
    size_t off_dinv    = off_hb + (size_t)N * DIM * 2;        // 12,800,000
    size_t off_rowbeg  = off_dinv + (size_t)N * 4;            // 13,200,000
    size_t off_rowend  = off_rowbeg + (size_t)N * 4;          // 13,600,000
    size_t off_entries = off_rowend + (size_t)N * 4;          // 14,000,000
    size_t off_partial = off_entries + (size_t)NBUCK * CAP_OUT * 4;  // 25,210,752
    size_t off_z       = off_partial + (size_t)GBLK * 128 * 4;       // 28,410,752 (mult of 128)

    unsigned short* hb    = (unsigned short*)(ws + off_hb);
    float*          dinv  = (float*)(ws + off_dinv);
    int*            rowbeg = (int*)(ws + off_rowbeg);
    int*            rowend = (int*)(ws + off_rowend);
    unsigned int*   entries = (unsigned int*)(ws + off_entries);
    float*          partial = (float*)(ws + off_partial);
    // zero region: dummy hb row [128 B] | cur[NBUCK] | gstat[128]
    int*   cur   = (int*)(ws + off_z + 128);
    float* gstat = (float*)(cur + NBUCK);
    int dummyIdx = (int)(off_z / (DIM * 2));             // hb row index of zero block

    size_t zbytes = 128 + (size_t)NBUCK * 4 + 512;       // 3768 B
    hipMemsetAsync(ws + off_z, 0, zbytes, stream);

    passA_kernel<<<ABLK, 1024, 0, stream>>>(src, dst, cur, entries, N_EDGES);

    build_kernel<<<NBUCK, 256, 0, stream>>>(entries, cur, rowbeg, rowend, dinv,
                                            x, W, hb, dummyIdx, N);

    gather_kernel<<<GBLK, 256, 0, stream>>>(rowbeg, rowend, entries, hb, dinv, out, partial, N);

    reduce2_kernel<<<50, 256, 0, stream>>>(partial, gstat);

    finish_kernel<<<(total / 4 + 255) / 256, 256, 0, stream>>>((float4*)out, gstat,
                                                               gamma, beta, total / 4, N);
}

// Round 14
// 191.000 us; speedup vs baseline: 6.8460x; 1.0164x over previous
//
#include <hip/hip_runtime.h>

#define N_NODES 100000
#define N_EDGES 1600000
#define DIM 64
#define BN_EPS 1e-5f

#define BNODES 128                        // nodes per bucket (7 bits)
#define NBUCK ((N_NODES + BNODES - 1) / BNODES)  // 782
#define CAP_RAW 2560                      // raw entries/bucket: mean 2046, +11 sigma
#define CAP_OUT 3584                      // sorted+padded capacity
#define TILE 4096                         // edges per passA block
#define ABLK ((N_EDGES + TILE - 1) / TILE)  // 391

#define GBLK 6250                         // gather blocks (4 waves x 4 nodes each)

typedef __bf16 bf16x8 __attribute__((ext_vector_type(8)));
typedef float floatx4 __attribute__((ext_vector_type(4)));

// ---- bf16 helpers (manual RNE) -------------------------------------------
static __device__ __forceinline__ unsigned short f2bf(float f) {
    unsigned u = __float_as_uint(f);
    u = (u + 0x7FFFu + ((u >> 16) & 1u)) >> 16;
    return (unsigned short)u;
}
static __device__ __forceinline__ float bf2f(unsigned short h) {
    return __uint_as_float(((unsigned)h) << 16);
}

// ---------------- passA: coarse partition into 128-node buckets -----------
__global__ void __launch_bounds__(1024)
passA_kernel(const int* __restrict__ src, const int* __restrict__ dst,
             int* __restrict__ cur, unsigned int* __restrict__ entries, int E) {
    __shared__ int hist[NBUCK];
    __shared__ int lbase[NBUCK];
    int t = threadIdx.x;
    if (t < NBUCK) hist[t] = 0;
    __syncthreads();

    int e0   = blockIdx.x * TILE;
    int eend = min(e0 + TILE, E);
    int eb   = e0 + t * 4;

    int dreg[4], sreg[4], ne = 0;
    if (eb + 3 < eend) {
        int4 d4 = *(const int4*)(dst + eb);
        int4 s4 = *(const int4*)(src + eb);
        dreg[0] = d4.x; dreg[1] = d4.y; dreg[2] = d4.z; dreg[3] = d4.w;
        sreg[0] = s4.x; sreg[1] = s4.y; sreg[2] = s4.z; sreg[3] = s4.w;
        ne = 4;
    } else {
        for (int e = eb; e < eend && ne < 4; ++e, ++ne) {
            dreg[ne] = dst[e];
            sreg[ne] = src[e];
        }
    }
#pragma unroll
    for (int k = 0; k < 4; ++k)
        if (k < ne) atomicAdd(&hist[dreg[k] >> 7], 1);
    __syncthreads();
    if (t < NBUCK) {
        int ii = t + (blockIdx.x * 331) % NBUCK;   // staggered start
        if (ii >= NBUCK) ii -= NBUCK;
        int c = hist[ii];
        lbase[ii] = (c > 0) ? atomicAdd(&cur[ii], c) : 0;
        hist[ii] = 0;                      // reuse as local cursor
    }
    __syncthreads();
#pragma unroll
    for (int k = 0; k < 4; ++k) {
        if (k >= ne) break;
        int s = sreg[k];
        int d = dreg[k];
        int b = d >> 7;
        int r = atomicAdd(&hist[b], 1);
        int pos = lbase[b] + r;
        if (pos < CAP_RAW)                // safety valve; statistically never
            entries[(size_t)b * CAP_OUT + pos] = ((unsigned)s << 7) | (unsigned)(d & 127);
    }
}

// ---------------- build: counting sort (node,src-quarter) + MFMA GEMM -----
__global__ void __launch_bounds__(256)
build_kernel(unsigned int* __restrict__ entries, const int* __restrict__ cur,
             int* __restrict__ rowbeg, int* __restrict__ rowend,
             float* __restrict__ dinv,
             const float* __restrict__ x, const float* __restrict__ W,
             unsigned short* __restrict__ hb, int dummyIdx, int N) {
    __shared__ unsigned int raw[CAP_RAW]; // 10 KB
    __shared__ int hist[BNODES * 4];      // per (node,quarter) counts
    __shared__ int sbuf[BNODES];
    __shared__ int nstart[BNODES];
    __shared__ int cursor[BNODES * 4];
    __shared__ float sdinv[BNODES];
    int bucket = blockIdx.x;
    int t = threadIdx.x;                  // 256 threads = 4 waves
    int node0 = bucket * BNODES;
    int nn = min(BNODES, N - node0);
    int cnt = min(cur[bucket], CAP_RAW);
    unsigned int* eb = entries + (size_t)bucket * CAP_OUT;

    for (int i = t; i < BNODES * 4; i += 256) hist[i] = 0;
    __syncthreads();
    for (int i = t; i < cnt; i += 256) {
        unsigned int e = eb[i];
        raw[i] = e;
        int s = (int)(e >> 7);
        int q = (s >= 25000) + (s >= 50000) + (s >= 75000);
        atomicAdd(&hist[((e & 127) << 2) | q], 1);
    }
    __syncthreads();
    int deg_t = 0, pdeg_t = 0;
    if (t < BNODES) {
        deg_t = hist[t * 4] + hist[t * 4 + 1] + hist[t * 4 + 2] + hist[t * 4 + 3];
        pdeg_t = (deg_t + 7) & ~7;
        sbuf[t] = pdeg_t;
    }
    __syncthreads();
    for (int off = 1; off < BNODES; off <<= 1) {
        int add = (t < BNODES && t >= off) ? sbuf[t - off] : 0;
        __syncthreads();
        if (t < BNODES) sbuf[t] += add;
        __syncthreads();
    }
    if (t < BNODES) {
        int ex = sbuf[t] - pdeg_t;        // exclusive padded node start
        nstart[t] = ex;
        int o = ex;
        cursor[t * 4 + 0] = o; o += hist[t * 4 + 0];
        cursor[t * 4 + 1] = o; o += hist[t * 4 + 1];
        cursor[t * 4 + 2] = o; o += hist[t * 4 + 2];
        cursor[t * 4 + 3] = o;
    }
    __syncthreads();
    for (int i = t; i < cnt; i += 256) {
        unsigned int e = raw[i];
        int s = (int)(e >> 7);
        int q = (s >= 25000) + (s >= 50000) + (s >= 75000);
        int p = atomicAdd(&cursor[((e & 127) << 2) | q], 1);
        eb[p] = (unsigned)s;              // store src only, quarter-sorted
    }
    if (t < nn) {
        int dg  = deg_t;
        int pdg = pdeg_t;
        int base = nstart[t];
        for (int k = dg; k < pdg; ++k) eb[base + k] = (unsigned)dummyIdx;
        int gbase = bucket * CAP_OUT + base;
        rowbeg[node0 + t] = gbase;
        rowend[node0 + t] = gbase + pdg;
        float di = rsqrtf((float)(dg + 1));  // self-loop included
        dinv[node0 + t] = di;
        sdinv[t] = di;
    }
    __syncthreads();

    // ---- GEMM phase (operand-swapped: lane = row, regs = 4 features) -----
    int lane = t & 63, wv = t >> 6;
    int m = lane & 15, quad = lane >> 4;
    int nchunk = nn >> 4;                 // 8 (last bucket: 2)
    bf16x8 bfrag[2][4];
#pragma unroll
    for (int c = 0; c < 2; ++c)
#pragma unroll
        for (int nt = 0; nt < 4; ++nt) {
            bf16x8 f;
#pragma unroll
            for (int j = 0; j < 8; ++j) {
                int k = c * 32 + quad * 8 + j;
                f[j] = (__bf16)W[k * DIM + nt * 16 + m];
            }
            bfrag[c][nt] = f;
        }
    for (int c2 = wv; c2 < nchunk; c2 += 4) {
        int lrow0 = c2 * 16;
        int row0 = node0 + lrow0;
        const float* xr = x + (size_t)(row0 + m) * DIM;
        bf16x8 afrag[2];
#pragma unroll
        for (int c = 0; c < 2; ++c) {
            float4 lo = *(const float4*)(xr + c * 32 + quad * 8);
            float4 hi = *(const float4*)(xr + c * 32 + quad * 8 + 4);
            bf16x8 f;
            f[0] = (__bf16)lo.x; f[1] = (__bf16)lo.y; f[2] = (__bf16)lo.z; f[3] = (__bf16)lo.w;
            f[4] = (__bf16)hi.x; f[5] = (__bf16)hi.y; f[6] = (__bf16)hi.z; f[7] = (__bf16)hi.w;
            afrag[c] = f;
        }
        float dv = sdinv[lrow0 + m];      // one dinv per lane (its row)
#pragma unroll
        for (int nt = 0; nt < 4; ++nt) {
            floatx4 acc = {0.f, 0.f, 0.f, 0.f};
            acc = __builtin_amdgcn_mfma_f32_16x16x32_bf16(bfrag[0][nt], afrag[0], acc, 0, 0, 0);
            acc = __builtin_amdgcn_mfma_f32_16x16x32_bf16(bfrag[1][nt], afrag[1], acc, 0, 0, 0);
            ushort4 pk;
            pk.x = f2bf(acc[0] * dv);
            pk.y = f2bf(acc[1] * dv);
            pk.z = f2bf(acc[2] * dv);
            pk.w = f2bf(acc[3] * dv);
            *(ushort4*)(hb + (size_t)(row0 + m) * DIM + nt * 16 + quad * 4) = pk;
        }
    }
}

// ---------------- gather: 4 nodes/wave, 16-edge double-chunk MLP ----------
// Two 8-edge chunks per iteration: all 16 row-loads issued before any
// consume (doubles loads in flight vs r13). Pre-BN result stored as bf16
// to hbout (half the write traffic); BN stats computed on ROUNDED values
// so the BN transform in finish is exact w.r.t. its input.
__global__ void __launch_bounds__(256)
gather_kernel(const int* __restrict__ rowbeg, const int* __restrict__ rowend,
              const unsigned int* __restrict__ srt, const unsigned short* __restrict__ hb,
              const float* __restrict__ dinv, unsigned short* __restrict__ hbout,
              float* __restrict__ partial, int N) {
    __shared__ float red[2][4][64];
    int lane = threadIdx.x & 63;
    int wv   = threadIdx.x >> 6;
    int g    = blockIdx.x * 4 + wv;
    int n0   = g << 2;
    float s_sum = 0.f, s_sq = 0.f;

    if (n0 < N) {  // uniform per wave; N % 4 == 0; groups never straddle buckets
        int beg = __builtin_amdgcn_readfirstlane(rowbeg[n0]);
        int s1  = __builtin_amdgcn_readfirstlane(rowbeg[n0 + 1]);
        int s2  = __builtin_amdgcn_readfirstlane(rowbeg[n0 + 2]);
        int s3  = __builtin_amdgcn_readfirstlane(rowbeg[n0 + 3]);
        int end = __builtin_amdgcn_readfirstlane(rowend[n0 + 3]);
        float acc0 = 0.f, acc1 = 0.f, acc2 = 0.f, acc3 = 0.f;

        for (int base = beg; base < end; base += 64) {
            int idx = base + lane;
            unsigned int sv = (idx < end) ? srt[idx] : 0u;  // coalesced batch
            int cn = min(64, end - base);                   // multiple of 8
            int j = 0;
            for (; j + 16 <= cn; j += 16) {                 // double chunk
                int pA = base + j;                          // uniform (SALU)
                int pB = pA + 8;
                int kA = (pA >= s1) + (pA >= s2) + (pA >= s3);
                int kB = (pB >= s1) + (pB >= s2) + (pB >= s3);
                float v[16];
#pragma unroll
                for (int u = 0; u < 16; ++u) {              // 16 loads in flight
                    unsigned int s = (unsigned)__builtin_amdgcn_readlane((int)sv, j + u);
                    v[u] = bf2f(hb[(size_t)s * DIM + lane]);
                }
                float cA = ((v[0] + v[1]) + (v[2] + v[3])) +
                           ((v[4] + v[5]) + (v[6] + v[7]));
                float cB = ((v[8] + v[9]) + (v[10] + v[11])) +
                           ((v[12] + v[13]) + (v[14] + v[15]));
                acc0 += (kA == 0) ? cA : 0.f;
                acc1 += (kA == 1) ? cA : 0.f;
                acc2 += (kA == 2) ? cA : 0.f;
                acc3 += (kA == 3) ? cA : 0.f;
                acc0 += (kB == 0) ? cB : 0.f;
                acc1 += (kB == 1) ? cB : 0.f;
                acc2 += (kB == 2) ? cB : 0.f;
                acc3 += (kB == 3) ? cB : 0.f;
            }
            for (; j < cn; j += 8) {                        // odd tail chunk
                int p0 = base + j;
                int k = (p0 >= s1) + (p0 >= s2) + (p0 >= s3);
                float v[8];
#pragma unroll
                for (int u = 0; u < 8; ++u) {
                    unsigned int s = (unsigned)__builtin_amdgcn_readlane((int)sv, j + u);
                    v[u] = bf2f(hb[(size_t)s * DIM + lane]);
                }
                float csum = ((v[0] + v[1]) + (v[2] + v[3])) +
                             ((v[4] + v[5]) + (v[6] + v[7]));
                acc0 += (k == 0) ? csum : 0.f;
                acc1 += (k == 1) ? csum : 0.f;
                acc2 += (k == 2) ? csum : 0.f;
                acc3 += (k == 3) ? csum : 0.f;
            }
        }

        float v0 = (acc0 + bf2f(hb[(size_t)(n0 + 0) * DIM + lane])) * dinv[n0 + 0];
        float v1 = (acc1 + bf2f(hb[(size_t)(n0 + 1) * DIM + lane])) * dinv[n0 + 1];
        float v2 = (acc2 + bf2f(hb[(size_t)(n0 + 2) * DIM + lane])) * dinv[n0 + 2];
        float v3 = (acc3 + bf2f(hb[(size_t)(n0 + 3) * DIM + lane])) * dinv[n0 + 3];
        unsigned short r0 = f2bf(v0), r1 = f2bf(v1), r2 = f2bf(v2), r3 = f2bf(v3);
        hbout[(size_t)(n0 + 0) * DIM + lane] = r0;
        hbout[(size_t)(n0 + 1) * DIM + lane] = r1;
        hbout[(size_t)(n0 + 2) * DIM + lane] = r2;
        hbout[(size_t)(n0 + 3) * DIM + lane] = r3;
        // stats on the ROUNDED values -> BN transform is exact w.r.t. input
        float w0 = bf2f(r0), w1 = bf2f(r1), w2 = bf2f(r2), w3 = bf2f(r3);
        s_sum = ((w0 + w1) + (w2 + w3));
        s_sq  = ((w0 * w0 + w1 * w1) + (w2 * w2 + w3 * w3));
    }

    red[0][wv][lane] = s_sum;
    red[1][wv][lane] = s_sq;
    __syncthreads();
    if (threadIdx.x < 64) {
        int c = threadIdx.x;
        partial[(size_t)blockIdx.x * 128 + c] =
            red[0][0][c] + red[0][1][c] + red[0][2][c] + red[0][3][c];
        partial[(size_t)blockIdx.x * 128 + 64 + c] =
            red[1][0][c] + red[1][1][c] + red[1][2][c] + red[1][3][c];
    }
}

// ---------------- reduce2: fold per-block BN partials ---------------------
__global__ void reduce2_kernel(const float* __restrict__ partial, float* __restrict__ gstat) {
    __shared__ float buf[256];
    int t = threadIdx.x;
    int col = t & 127;
    int half = t >> 7;                    // 0 or 1
    int r0 = blockIdx.x * 125;            // 50 blocks x 125 rows = 6250
    float acc = 0.f;
    for (int r = r0 + half; r < r0 + 125; r += 2)
        acc += partial[(size_t)r * 128 + col];
    buf[t] = acc;
    __syncthreads();
    if (t < 128) atomicAdd(&gstat[t], buf[t] + buf[t + 128]);  // gsum[64]|gsumsq[64]
}

// ---------------- finish: BN finalize + apply + ReLU (bf16 in, f32 out) ---
// bias b cancels in BN (uniform per-column shift), so it's omitted entirely.
__global__ void __launch_bounds__(256)
finish_kernel(const ushort4* __restrict__ hbo, float4* __restrict__ out,
              const float* __restrict__ gstat,
              const float* __restrict__ gamma, const float* __restrict__ beta,
              int total4, int N) {
    __shared__ float scale[64];
    __shared__ float shift[64];
    int t = threadIdx.x;
    if (t < 64) {
        float invN = 1.0f / (float)N;
        float mean = gstat[t] * invN;
        float var  = gstat[64 + t] * invN - mean * mean;
        float sc   = gamma[t] * rsqrtf(var + BN_EPS);
        scale[t] = sc;
        shift[t] = beta[t] - mean * sc;
    }
    __syncthreads();
    int i = blockIdx.x * blockDim.x + t;
    if (i >= total4) return;
    int c = (i * 4) & 63;
    ushort4 u = hbo[i];
    float4 v;
    float a0 = fmaf(bf2f(u.x), scale[c],     shift[c]);
    float a1 = fmaf(bf2f(u.y), scale[c + 1], shift[c + 1]);
    float a2 = fmaf(bf2f(u.z), scale[c + 2], shift[c + 2]);
    float a3 = fmaf(bf2f(u.w), scale[c + 3], shift[c + 3]);
    v.x = a0 > 0.f ? a0 : 0.f;
    v.y = a1 > 0.f ? a1 : 0.f;
    v.z = a2 > 0.f ? a2 : 0.f;
    v.w = a3 > 0.f ? a3 : 0.f;
    out[i] = v;
}

extern "C" void kernel_launch(void* const* d_in, const int* in_sizes, int n_in,
                              void* d_out, int out_size, void* d_ws, size_t ws_size,
                              hipStream_t stream) {
    const float* x     = (const float*)d_in[0];          // [N, 64]
    const int*   eidx  = (const int*)d_in[1];            // [2, E]
    const float* W     = (const float*)d_in[2];          // [64, 64]
    // d_in[3] = b : cancels in BatchNorm (uniform per-column shift)
    const float* gamma = (const float*)d_in[4];          // [64]
    const float* beta  = (const float*)d_in[5];          // [64]
    float* out = (float*)d_out;                          // [N, 64]

    const int N = N_NODES;
    const int total = N * DIM;

    const int* src = eidx;
    const int* dst = eidx + N_EDGES;

    // workspace layout (byte offsets; hb rows are 128 B)
    char* ws = (char*)d_ws;
    size_t off_hb      = 0;                                   // N*128 = 12,800,000
    size_t off_hbout   = off_hb + (size_t)N * DIM * 2;        // 12,800,000 (pre-BN bf16)
    size_t off_dinv    = off_hbout + (size_t)N * DIM * 2;     // 25,600,000
    size_t off_rowbeg  = off_dinv + (size_t)N * 4;            // 26,000,000
    size_t off_rowend  = off_rowbeg + (size_t)N * 4;          // 26,400,000
    size_t off_entries = off_rowend + (size_t)N * 4;          // 26,800,000
    size_t off_partial = off_entries + (size_t)NBUCK * CAP_OUT * 4;  // 38,010,752
    size_t off_z       = off_partial + (size_t)GBLK * 128 * 4;       // 41,210,752 (mult 128)

    unsigned short* hb     = (unsigned short*)(ws + off_hb);
    unsigned short* hbout  = (unsigned short*)(ws + off_hbout);
    float*          dinv   = (float*)(ws + off_dinv);
    int*            rowbeg = (int*)(ws + off_rowbeg);
    int*            rowend = (int*)(ws + off_rowend);
    unsigned int*   entries = (unsigned int*)(ws + off_entries);
    float*          partial = (float*)(ws + off_partial);
    // zero region: dummy hb row [128 B] | cur[NBUCK] | gstat[128]
    int*   cur   = (int*)(ws + off_z + 128);
    float* gstat = (float*)(cur + NBUCK);
    int dummyIdx = (int)(off_z / (DIM * 2));             // hb row index of zero block

    size_t zbytes = 128 + (size_t)NBUCK * 4 + 512;       // 3768 B
    hipMemsetAsync(ws + off_z, 0, zbytes, stream);

    passA_kernel<<<ABLK, 1024, 0, stream>>>(src, dst, cur, entries, N_EDGES);

    build_kernel<<<NBUCK, 256, 0, stream>>>(entries, cur, rowbeg, rowend, dinv,
                                            x, W, hb, dummyIdx, N);

    gather_kernel<<<GBLK, 256, 0, stream>>>(rowbeg, rowend, entries, hb, dinv,
                                            hbout, partial, N);

    reduce2_kernel<<<50, 256, 0, stream>>>(partial, gstat);

    finish_kernel<<<(total / 4 + 255) / 256, 256, 0, stream>>>((const ushort4*)hbout,
                                                               (float4*)out, gstat,
                                                               gamma, beta, total / 4, N);
}

// Round 15
// 173.892 us; speedup vs baseline: 7.5195x; 1.0984x over previous
//
#include <hip/hip_runtime.h>

#define N_NODES 100000
#define N_EDGES 1600000
#define DIM 64
#define BN_EPS 1e-5f

#define BNODES 128                        // nodes per bucket (7 bits)
#define NBUCK ((N_NODES + BNODES - 1) / BNODES)  // 782
#define CAP_RAW 2560                      // raw entries/bucket: mean 2046, +11 sigma
#define CAP_OUT 3584                      // sorted+padded capacity
#define TILE 4096                         // edges per passA block
#define ABLK ((N_EDGES + TILE - 1) / TILE)  // 391

#define GBLK 6250                         // gather blocks (4 waves x 4 nodes each)
#define NREP 32                           // replicated BN-stat accumulators

typedef __bf16 bf16x8 __attribute__((ext_vector_type(8)));
typedef float floatx4 __attribute__((ext_vector_type(4)));

// ---- bf16 helpers (manual RNE) -------------------------------------------
static __device__ __forceinline__ unsigned short f2bf(float f) {
    unsigned u = __float_as_uint(f);
    u = (u + 0x7FFFu + ((u >> 16) & 1u)) >> 16;
    return (unsigned short)u;
}
static __device__ __forceinline__ float bf2f(unsigned short h) {
    return __uint_as_float(((unsigned)h) << 16);
}

// ---------------- passA: coarse partition into 128-node buckets -----------
__global__ void __launch_bounds__(1024)
passA_kernel(const int* __restrict__ src, const int* __restrict__ dst,
             int* __restrict__ cur, unsigned int* __restrict__ entries, int E) {
    __shared__ int hist[NBUCK];
    __shared__ int lbase[NBUCK];
    int t = threadIdx.x;
    if (t < NBUCK) hist[t] = 0;
    __syncthreads();

    int e0   = blockIdx.x * TILE;
    int eend = min(e0 + TILE, E);
    int eb   = e0 + t * 4;

    int dreg[4], sreg[4], ne = 0;
    if (eb + 3 < eend) {
        int4 d4 = *(const int4*)(dst + eb);
        int4 s4 = *(const int4*)(src + eb);
        dreg[0] = d4.x; dreg[1] = d4.y; dreg[2] = d4.z; dreg[3] = d4.w;
        sreg[0] = s4.x; sreg[1] = s4.y; sreg[2] = s4.z; sreg[3] = s4.w;
        ne = 4;
    } else {
        for (int e = eb; e < eend && ne < 4; ++e, ++ne) {
            dreg[ne] = dst[e];
            sreg[ne] = src[e];
        }
    }
#pragma unroll
    for (int k = 0; k < 4; ++k)
        if (k < ne) atomicAdd(&hist[dreg[k] >> 7], 1);
    __syncthreads();
    if (t < NBUCK) {
        int ii = t + (blockIdx.x * 331) % NBUCK;   // staggered start
        if (ii >= NBUCK) ii -= NBUCK;
        int c = hist[ii];
        lbase[ii] = (c > 0) ? atomicAdd(&cur[ii], c) : 0;
        hist[ii] = 0;                      // reuse as local cursor
    }
    __syncthreads();
#pragma unroll
    for (int k = 0; k < 4; ++k) {
        if (k >= ne) break;
        int s = sreg[k];
        int d = dreg[k];
        int b = d >> 7;
        int r = atomicAdd(&hist[b], 1);
        int pos = lbase[b] + r;
        if (pos < CAP_RAW)                // safety valve; statistically never
            entries[(size_t)b * CAP_OUT + pos] = ((unsigned)s << 7) | (unsigned)(d & 127);
    }
}

// ---------------- build: counting sort (node,src-quarter) + MFMA GEMM -----
__global__ void __launch_bounds__(256)
build_kernel(unsigned int* __restrict__ entries, const int* __restrict__ cur,
             int* __restrict__ rowbeg, int* __restrict__ rowend,
             float* __restrict__ dinv,
             const float* __restrict__ x, const float* __restrict__ W,
             unsigned short* __restrict__ hb, int dummyIdx, int N) {
    __shared__ unsigned int raw[CAP_RAW]; // 10 KB
    __shared__ int hist[BNODES * 4];      // per (node,quarter) counts
    __shared__ int sbuf[BNODES];
    __shared__ int nstart[BNODES];
    __shared__ int cursor[BNODES * 4];
    __shared__ float sdinv[BNODES];
    int bucket = blockIdx.x;
    int t = threadIdx.x;                  // 256 threads = 4 waves
    int node0 = bucket * BNODES;
    int nn = min(BNODES, N - node0);
    int cnt = min(cur[bucket], CAP_RAW);
    unsigned int* eb = entries + (size_t)bucket * CAP_OUT;

    for (int i = t; i < BNODES * 4; i += 256) hist[i] = 0;
    __syncthreads();
    for (int i = t; i < cnt; i += 256) {
        unsigned int e = eb[i];
        raw[i] = e;
        int s = (int)(e >> 7);
        int q = (s >= 25000) + (s >= 50000) + (s >= 75000);
        atomicAdd(&hist[((e & 127) << 2) | q], 1);
    }
    __syncthreads();
    int deg_t = 0, pdeg_t = 0;
    if (t < BNODES) {
        deg_t = hist[t * 4] + hist[t * 4 + 1] + hist[t * 4 + 2] + hist[t * 4 + 3];
        pdeg_t = (deg_t + 7) & ~7;
        sbuf[t] = pdeg_t;
    }
    __syncthreads();
    for (int off = 1; off < BNODES; off <<= 1) {
        int add = (t < BNODES && t >= off) ? sbuf[t - off] : 0;
        __syncthreads();
        if (t < BNODES) sbuf[t] += add;
        __syncthreads();
    }
    if (t < BNODES) {
        int ex = sbuf[t] - pdeg_t;        // exclusive padded node start
        nstart[t] = ex;
        int o = ex;
        cursor[t * 4 + 0] = o; o += hist[t * 4 + 0];
        cursor[t * 4 + 1] = o; o += hist[t * 4 + 1];
        cursor[t * 4 + 2] = o; o += hist[t * 4 + 2];
        cursor[t * 4 + 3] = o;
    }
    __syncthreads();
    for (int i = t; i < cnt; i += 256) {
        unsigned int e = raw[i];
        int s = (int)(e >> 7);
        int q = (s >= 25000) + (s >= 50000) + (s >= 75000);
        int p = atomicAdd(&cursor[((e & 127) << 2) | q], 1);
        eb[p] = (unsigned)s;              // store src only, quarter-sorted
    }
    if (t < nn) {
        int dg  = deg_t;
        int pdg = pdeg_t;
        int base = nstart[t];
        for (int k = dg; k < pdg; ++k) eb[base + k] = (unsigned)dummyIdx;
        int gbase = bucket * CAP_OUT + base;
        rowbeg[node0 + t] = gbase;
        rowend[node0 + t] = gbase + pdg;
        float di = rsqrtf((float)(dg + 1));  // self-loop included
        dinv[node0 + t] = di;
        sdinv[t] = di;
    }
    __syncthreads();

    // ---- GEMM phase (operand-swapped: lane = row, regs = 4 features) -----
    int lane = t & 63, wv = t >> 6;
    int m = lane & 15, quad = lane >> 4;
    int nchunk = nn >> 4;                 // 8 (last bucket: 2)
    bf16x8 bfrag[2][4];
#pragma unroll
    for (int c = 0; c < 2; ++c)
#pragma unroll
        for (int nt = 0; nt < 4; ++nt) {
            bf16x8 f;
#pragma unroll
            for (int j = 0; j < 8; ++j) {
                int k = c * 32 + quad * 8 + j;
                f[j] = (__bf16)W[k * DIM + nt * 16 + m];
            }
            bfrag[c][nt] = f;
        }
    for (int c2 = wv; c2 < nchunk; c2 += 4) {
        int lrow0 = c2 * 16;
        int row0 = node0 + lrow0;
        const float* xr = x + (size_t)(row0 + m) * DIM;
        bf16x8 afrag[2];
#pragma unroll
        for (int c = 0; c < 2; ++c) {
            float4 lo = *(const float4*)(xr + c * 32 + quad * 8);
            float4 hi = *(const float4*)(xr + c * 32 + quad * 8 + 4);
            bf16x8 f;
            f[0] = (__bf16)lo.x; f[1] = (__bf16)lo.y; f[2] = (__bf16)lo.z; f[3] = (__bf16)lo.w;
            f[4] = (__bf16)hi.x; f[5] = (__bf16)hi.y; f[6] = (__bf16)hi.z; f[7] = (__bf16)hi.w;
            afrag[c] = f;
        }
        float dv = sdinv[lrow0 + m];      // one dinv per lane (its row)
#pragma unroll
        for (int nt = 0; nt < 4; ++nt) {
            floatx4 acc = {0.f, 0.f, 0.f, 0.f};
            acc = __builtin_amdgcn_mfma_f32_16x16x32_bf16(bfrag[0][nt], afrag[0], acc, 0, 0, 0);
            acc = __builtin_amdgcn_mfma_f32_16x16x32_bf16(bfrag[1][nt], afrag[1], acc, 0, 0, 0);
            ushort4 pk;
            pk.x = f2bf(acc[0] * dv);
            pk.y = f2bf(acc[1] * dv);
            pk.z = f2bf(acc[2] * dv);
            pk.w = f2bf(acc[3] * dv);
            *(ushort4*)(hb + (size_t)(row0 + m) * DIM + nt * 16 + quad * 4) = pk;
        }
    }
}

// ---------------- gather: 4 nodes/wave, 16-edge MLP, sv prefetch ----------
// BN partials go straight to one of NREP replicated gstat copies (blk&31):
// 32x less same-line contention than a single copy; reduce2 kernel deleted.
__global__ void __launch_bounds__(256)
gather_kernel(const int* __restrict__ rowbeg, const int* __restrict__ rowend,
              const unsigned int* __restrict__ srt, const unsigned short* __restrict__ hb,
              const float* __restrict__ dinv, unsigned short* __restrict__ hbout,
              float* __restrict__ gstatRep, int N) {
    __shared__ float red[2][4][64];
    int lane = threadIdx.x & 63;
    int wv   = threadIdx.x >> 6;
    int g    = blockIdx.x * 4 + wv;
    int n0   = g << 2;
    float s_sum = 0.f, s_sq = 0.f;

    if (n0 < N) {  // uniform per wave; N % 4 == 0; groups never straddle buckets
        int beg = __builtin_amdgcn_readfirstlane(rowbeg[n0]);
        int s1  = __builtin_amdgcn_readfirstlane(rowbeg[n0 + 1]);
        int s2  = __builtin_amdgcn_readfirstlane(rowbeg[n0 + 2]);
        int s3  = __builtin_amdgcn_readfirstlane(rowbeg[n0 + 3]);
        int end = __builtin_amdgcn_readfirstlane(rowend[n0 + 3]);
        float acc0 = 0.f, acc1 = 0.f, acc2 = 0.f, acc3 = 0.f;

        unsigned int sv = (beg + lane < end) ? srt[beg + lane] : 0u;
        for (int base = beg; base < end; base += 64) {
            // prefetch next index batch before consuming this one
            int nidx = base + 64 + lane;
            unsigned int sv_next = (nidx < end) ? srt[nidx] : 0u;
            int cn = min(64, end - base);                   // multiple of 8
            int j = 0;
            for (; j + 16 <= cn; j += 16) {                 // double chunk
                int pA = base + j;                          // uniform (SALU)
                int pB = pA + 8;
                int kA = (pA >= s1) + (pA >= s2) + (pA >= s3);
                int kB = (pB >= s1) + (pB >= s2) + (pB >= s3);
                float v[16];
#pragma unroll
                for (int u = 0; u < 16; ++u) {              // 16 loads in flight
                    unsigned int s = (unsigned)__builtin_amdgcn_readlane((int)sv, j + u);
                    v[u] = bf2f(hb[(size_t)s * DIM + lane]);
                }
                float cA = ((v[0] + v[1]) + (v[2] + v[3])) +
                           ((v[4] + v[5]) + (v[6] + v[7]));
                float cB = ((v[8] + v[9]) + (v[10] + v[11])) +
                           ((v[12] + v[13]) + (v[14] + v[15]));
                acc0 += (kA == 0) ? cA : 0.f;
                acc1 += (kA == 1) ? cA : 0.f;
                acc2 += (kA == 2) ? cA : 0.f;
                acc3 += (kA == 3) ? cA : 0.f;
                acc0 += (kB == 0) ? cB : 0.f;
                acc1 += (kB == 1) ? cB : 0.f;
                acc2 += (kB == 2) ? cB : 0.f;
                acc3 += (kB == 3) ? cB : 0.f;
            }
            for (; j < cn; j += 8) {                        // odd tail chunk
                int p0 = base + j;
                int k = (p0 >= s1) + (p0 >= s2) + (p0 >= s3);
                float v[8];
#pragma unroll
                for (int u = 0; u < 8; ++u) {
                    unsigned int s = (unsigned)__builtin_amdgcn_readlane((int)sv, j + u);
                    v[u] = bf2f(hb[(size_t)s * DIM + lane]);
                }
                float csum = ((v[0] + v[1]) + (v[2] + v[3])) +
                             ((v[4] + v[5]) + (v[6] + v[7]));
                acc0 += (k == 0) ? csum : 0.f;
                acc1 += (k == 1) ? csum : 0.f;
                acc2 += (k == 2) ? csum : 0.f;
                acc3 += (k == 3) ? csum : 0.f;
            }
            sv = sv_next;
        }

        float v0 = (acc0 + bf2f(hb[(size_t)(n0 + 0) * DIM + lane])) * dinv[n0 + 0];
        float v1 = (acc1 + bf2f(hb[(size_t)(n0 + 1) * DIM + lane])) * dinv[n0 + 1];
        float v2 = (acc2 + bf2f(hb[(size_t)(n0 + 2) * DIM + lane])) * dinv[n0 + 2];
        float v3 = (acc3 + bf2f(hb[(size_t)(n0 + 3) * DIM + lane])) * dinv[n0 + 3];
        unsigned short r0 = f2bf(v0), r1 = f2bf(v1), r2 = f2bf(v2), r3 = f2bf(v3);
        hbout[(size_t)(n0 + 0) * DIM + lane] = r0;
        hbout[(size_t)(n0 + 1) * DIM + lane] = r1;
        hbout[(size_t)(n0 + 2) * DIM + lane] = r2;
        hbout[(size_t)(n0 + 3) * DIM + lane] = r3;
        // stats on the ROUNDED values -> BN transform is exact w.r.t. input
        float w0 = bf2f(r0), w1 = bf2f(r1), w2 = bf2f(r2), w3 = bf2f(r3);
        s_sum = ((w0 + w1) + (w2 + w3));
        s_sq  = ((w0 * w0 + w1 * w1) + (w2 * w2 + w3 * w3));
    }

    red[0][wv][lane] = s_sum;
    red[1][wv][lane] = s_sq;
    __syncthreads();
    if (threadIdx.x < 128) {
        int c = threadIdx.x & 63;
        int which = threadIdx.x >> 6;     // 0 = sum, 1 = sumsq
        float v = red[which][0][c] + red[which][1][c] + red[which][2][c] + red[which][3][c];
        float* dst = gstatRep + (size_t)(blockIdx.x & (NREP - 1)) * 128 + which * 64 + c;
        atomicAdd(dst, v);
    }
}

// ---------------- finish: fold NREP stat copies + BN + ReLU ---------------
// bias b cancels in BN (uniform per-column shift), so it's omitted entirely.
__global__ void __launch_bounds__(256)
finish_kernel(const ushort4* __restrict__ hbo, float4* __restrict__ out,
              const float* __restrict__ gstatRep,
              const float* __restrict__ gamma, const float* __restrict__ beta,
              int total4, int N) {
    __shared__ float scale[64];
    __shared__ float shift[64];
    int t = threadIdx.x;
    if (t < 128) {
        int c = t & 63;
        int which = t >> 6;
        float acc = 0.f;
#pragma unroll
        for (int r = 0; r < NREP; ++r)
            acc += gstatRep[(size_t)r * 128 + which * 64 + c];
        red_store:;
        __shared__ float stat[128];
        stat[t] = acc;
        __syncthreads();
        if (t < 64) {
            float invN = 1.0f / (float)N;
            float mean = stat[t] * invN;
            float var  = stat[64 + t] * invN - mean * mean;
            float sc   = gamma[t] * rsqrtf(var + BN_EPS);
            scale[t] = sc;
            shift[t] = beta[t] - mean * sc;
        }
    } else {
        __syncthreads();
    }
    __syncthreads();
    int i = blockIdx.x * blockDim.x + t;
    if (i >= total4) return;
    int c = (i * 4) & 63;
    ushort4 u = hbo[i];
    float4 v;
    float a0 = fmaf(bf2f(u.x), scale[c],     shift[c]);
    float a1 = fmaf(bf2f(u.y), scale[c + 1], shift[c + 1]);
    float a2 = fmaf(bf2f(u.z), scale[c + 2], shift[c + 2]);
    float a3 = fmaf(bf2f(u.w), scale[c + 3], shift[c + 3]);
    v.x = a0 > 0.f ? a0 : 0.f;
    v.y = a1 > 0.f ? a1 : 0.f;
    v.z = a2 > 0.f ? a2 : 0.f;
    v.w = a3 > 0.f ? a3 : 0.f;
    out[i] = v;
}

extern "C" void kernel_launch(void* const* d_in, const int* in_sizes, int n_in,
                              void* d_out, int out_size, void* d_ws, size_t ws_size,
                              hipStream_t stream) {
    const float* x     = (const float*)d_in[0];          // [N, 64]
    const int*   eidx  = (const int*)d_in[1];            // [2, E]
    const float* W     = (const float*)d_in[2];          // [64, 64]
    // d_in[3] = b : cancels in BatchNorm (uniform per-column shift)
    const float* gamma = (const float*)d_in[4];          // [64]
    const float* beta  = (const float*)d_in[5];          // [64]
    float* out = (float*)d_out;                          // [N, 64]

    const int N = N_NODES;
    const int total = N * DIM;

    const int* src = eidx;
    const int* dst = eidx + N_EDGES;

    // workspace layout (byte offsets; hb rows are 128 B)
    char* ws = (char*)d_ws;
    size_t off_hb      = 0;                                   // N*128 = 12,800,000
    size_t off_hbout   = off_hb + (size_t)N * DIM * 2;        // 12,800,000 (pre-BN bf16)
    size_t off_dinv    = off_hbout + (size_t)N * DIM * 2;     // 25,600,000
    size_t off_rowbeg  = off_dinv + (size_t)N * 4;            // 26,000,000
    size_t off_rowend  = off_rowbeg + (size_t)N * 4;          // 26,400,000
    size_t off_entries = off_rowend + (size_t)N * 4;          // 26,800,000
    size_t off_z       = off_entries + (size_t)NBUCK * CAP_OUT * 4;  // 38,010,752 (mult 128)

    unsigned short* hb     = (unsigned short*)(ws + off_hb);
    unsigned short* hbout  = (unsigned short*)(ws + off_hbout);
    float*          dinv   = (float*)(ws + off_dinv);
    int*            rowbeg = (int*)(ws + off_rowbeg);
    int*            rowend = (int*)(ws + off_rowend);
    unsigned int*   entries = (unsigned int*)(ws + off_entries);
    // zero region: dummy hb row [128 B] | cur[NBUCK] | gstatRep[NREP*128]
    int*   cur      = (int*)(ws + off_z + 128);
    float* gstatRep = (float*)(cur + NBUCK);
    int dummyIdx = (int)(off_z / (DIM * 2));             // hb row index of zero block

    size_t zbytes = 128 + (size_t)NBUCK * 4 + (size_t)NREP * 128 * 4;  // 19,640 B
    hipMemsetAsync(ws + off_z, 0, zbytes, stream);

    passA_kernel<<<ABLK, 1024, 0, stream>>>(src, dst, cur, entries, N_EDGES);

    build_kernel<<<NBUCK, 256, 0, stream>>>(entries, cur, rowbeg, rowend, dinv,
                                            x, W, hb, dummyIdx, N);

    gather_kernel<<<GBLK, 256, 0, stream>>>(rowbeg, rowend, entries, hb, dinv,
                                            hbout, gstatRep, N);

    finish_kernel<<<(total / 4 + 255) / 256, 256, 0, stream>>>((const ushort4*)hbout,
                                                               (float4*)out, gstatRep,
                                                               gamma, beta, total / 4, N);
}

// Round 16
// 173.809 us; speedup vs baseline: 7.5231x; 1.0005x over previous
//
#include <hip/hip_runtime.h>

#define N_NODES 100000
#define N_EDGES 1600000
#define DIM 64
#define BN_EPS 1e-5f

#define BNODES 128                        // nodes per bucket (7 bits)
#define NBUCK ((N_NODES + BNODES - 1) / BNODES)  // 782
#define CAP_RAW 2560                      // raw entries/bucket: mean 2046, +11 sigma
#define CAP_OUT 3584                      // sorted+padded capacity
#define TILE 4096                         // edges per passA block
#define ABLK ((N_EDGES + TILE - 1) / TILE)  // 391

#define GBLK 6250                         // gather blocks (4 waves x 4 nodes each)
#define NREP 32                           // replicated BN-stat accumulators

typedef __bf16 bf16x8 __attribute__((ext_vector_type(8)));
typedef float floatx4 __attribute__((ext_vector_type(4)));

// ---- bf16 helpers (manual RNE) -------------------------------------------
static __device__ __forceinline__ unsigned short f2bf(float f) {
    unsigned u = __float_as_uint(f);
    u = (u + 0x7FFFu + ((u >> 16) & 1u)) >> 16;
    return (unsigned short)u;
}
static __device__ __forceinline__ float bf2f(unsigned short h) {
    return __uint_as_float(((unsigned)h) << 16);
}

// ---------------- passA: coarse partition into 128-node buckets -----------
__global__ void __launch_bounds__(1024)
passA_kernel(const int* __restrict__ src, const int* __restrict__ dst,
             int* __restrict__ cur, unsigned int* __restrict__ entries, int E) {
    __shared__ int hist[NBUCK];
    __shared__ int lbase[NBUCK];
    int t = threadIdx.x;
    if (t < NBUCK) hist[t] = 0;
    __syncthreads();

    int e0   = blockIdx.x * TILE;
    int eend = min(e0 + TILE, E);
    int eb   = e0 + t * 4;

    int dreg[4], sreg[4], ne = 0;
    if (eb + 3 < eend) {
        int4 d4 = *(const int4*)(dst + eb);
        int4 s4 = *(const int4*)(src + eb);
        dreg[0] = d4.x; dreg[1] = d4.y; dreg[2] = d4.z; dreg[3] = d4.w;
        sreg[0] = s4.x; sreg[1] = s4.y; sreg[2] = s4.z; sreg[3] = s4.w;
        ne = 4;
    } else {
        for (int e = eb; e < eend && ne < 4; ++e, ++ne) {
            dreg[ne] = dst[e];
            sreg[ne] = src[e];
        }
    }
#pragma unroll
    for (int k = 0; k < 4; ++k)
        if (k < ne) atomicAdd(&hist[dreg[k] >> 7], 1);
    __syncthreads();
    if (t < NBUCK) {
        int ii = t + (blockIdx.x * 331) % NBUCK;   // staggered start
        if (ii >= NBUCK) ii -= NBUCK;
        int c = hist[ii];
        lbase[ii] = (c > 0) ? atomicAdd(&cur[ii], c) : 0;
        hist[ii] = 0;                      // reuse as local cursor
    }
    __syncthreads();
#pragma unroll
    for (int k = 0; k < 4; ++k) {
        if (k >= ne) break;
        int s = sreg[k];
        int d = dreg[k];
        int b = d >> 7;
        int r = atomicAdd(&hist[b], 1);
        int pos = lbase[b] + r;
        if (pos < CAP_RAW)                // safety valve; statistically never
            entries[(size_t)b * CAP_OUT + pos] = ((unsigned)s << 7) | (unsigned)(d & 127);
    }
}

// ---------------- build: register-sort (node,src-quarter) + MFMA GEMM -----
// Entries held in a fully-unrolled 10-slot register array (no LDS raw[]
// round-trip); the 128-wide padded-degree scan is two wave-internal
// __shfl_up scans + one LDS handoff (3 barriers instead of 14).
__global__ void __launch_bounds__(256)
build_kernel(unsigned int* __restrict__ entries, const int* __restrict__ cur,
             int* __restrict__ rowbeg, int* __restrict__ rowend,
             float* __restrict__ dinv,
             const float* __restrict__ x, const float* __restrict__ W,
             unsigned short* __restrict__ hb, int dummyIdx, int N) {
    __shared__ int hist[BNODES * 4];      // per (node,quarter) counts
    __shared__ int nstart[BNODES];
    __shared__ int cursor[BNODES * 4];
    __shared__ float sdinv[BNODES];
    __shared__ int w0tot;
    int bucket = blockIdx.x;
    int t = threadIdx.x;                  // 256 threads = 4 waves
    int lane = t & 63, wv = t >> 6;
    int node0 = bucket * BNODES;
    int nn = min(BNODES, N - node0);
    int cnt = min(cur[bucket], CAP_RAW);
    unsigned int* eb = entries + (size_t)bucket * CAP_OUT;

    for (int i = t; i < BNODES * 4; i += 256) hist[i] = 0;
    __syncthreads();

    unsigned int ereg[10];                // CAP_RAW/256 = 10 slots, unrolled
#pragma unroll
    for (int k = 0; k < 10; ++k) {
        int i = t + k * 256;
        if (i < cnt) {
            unsigned int e = eb[i];
            ereg[k] = e;
            int s = (int)(e >> 7);
            int q = (s >= 25000) + (s >= 50000) + (s >= 75000);
            atomicAdd(&hist[((e & 127) << 2) | q], 1);
        }
    }
    __syncthreads();

    // padded degree + 128-wide exclusive scan via two wave-internal scans
    int deg_t = 0, pdeg_t = 0;
    if (t < BNODES) {
        deg_t = hist[t * 4] + hist[t * 4 + 1] + hist[t * 4 + 2] + hist[t * 4 + 3];
        pdeg_t = (deg_t + 7) & ~7;
    }
    int v = pdeg_t;                       // inclusive scan within wave
#pragma unroll
    for (int off = 1; off < 64; off <<= 1) {
        int u = __shfl_up(v, off, 64);
        if (lane >= off) v += u;
    }
    if (t == 63) w0tot = v;               // wave-0 total
    __syncthreads();
    if (t < BNODES) {
        int incl = v + (wv == 1 ? w0tot : 0);
        int ex = incl - pdeg_t;           // exclusive padded node start
        nstart[t] = ex;
        int o = ex;
        cursor[t * 4 + 0] = o; o += hist[t * 4 + 0];
        cursor[t * 4 + 1] = o; o += hist[t * 4 + 1];
        cursor[t * 4 + 2] = o; o += hist[t * 4 + 2];
        cursor[t * 4 + 3] = o;
    }
    __syncthreads();
#pragma unroll
    for (int k = 0; k < 10; ++k) {
        int i = t + k * 256;
        if (i < cnt) {
            unsigned int e = ereg[k];
            int s = (int)(e >> 7);
            int q = (s >= 25000) + (s >= 50000) + (s >= 75000);
            int p = atomicAdd(&cursor[((e & 127) << 2) | q], 1);
            eb[p] = (unsigned)s;          // store src only, quarter-sorted
        }
    }
    if (t < nn) {
        int dg  = deg_t;
        int pdg = pdeg_t;
        int base = nstart[t];
        for (int k = dg; k < pdg; ++k) eb[base + k] = (unsigned)dummyIdx;
        int gbase = bucket * CAP_OUT + base;
        rowbeg[node0 + t] = gbase;
        rowend[node0 + t] = gbase + pdg;
        float di = rsqrtf((float)(dg + 1));  // self-loop included
        dinv[node0 + t] = di;
        sdinv[t] = di;
    }
    __syncthreads();

    // ---- GEMM phase (operand-swapped: lane = row, regs = 4 features) -----
    int m = lane & 15, quad = lane >> 4;
    int nchunk = nn >> 4;                 // 8 (last bucket: 2)
    bf16x8 bfrag[2][4];
#pragma unroll
    for (int c = 0; c < 2; ++c)
#pragma unroll
        for (int nt = 0; nt < 4; ++nt) {
            bf16x8 f;
#pragma unroll
            for (int j = 0; j < 8; ++j) {
                int k = c * 32 + quad * 8 + j;
                f[j] = (__bf16)W[k * DIM + nt * 16 + m];
            }
            bfrag[c][nt] = f;
        }
    for (int c2 = wv; c2 < nchunk; c2 += 4) {
        int lrow0 = c2 * 16;
        int row0 = node0 + lrow0;
        const float* xr = x + (size_t)(row0 + m) * DIM;
        bf16x8 afrag[2];
#pragma unroll
        for (int c = 0; c < 2; ++c) {
            float4 lo = *(const float4*)(xr + c * 32 + quad * 8);
            float4 hi = *(const float4*)(xr + c * 32 + quad * 8 + 4);
            bf16x8 f;
            f[0] = (__bf16)lo.x; f[1] = (__bf16)lo.y; f[2] = (__bf16)lo.z; f[3] = (__bf16)lo.w;
            f[4] = (__bf16)hi.x; f[5] = (__bf16)hi.y; f[6] = (__bf16)hi.z; f[7] = (__bf16)hi.w;
            afrag[c] = f;
        }
        float dv = sdinv[lrow0 + m];      // one dinv per lane (its row)
#pragma unroll
        for (int nt = 0; nt < 4; ++nt) {
            floatx4 acc = {0.f, 0.f, 0.f, 0.f};
            acc = __builtin_amdgcn_mfma_f32_16x16x32_bf16(bfrag[0][nt], afrag[0], acc, 0, 0, 0);
            acc = __builtin_amdgcn_mfma_f32_16x16x32_bf16(bfrag[1][nt], afrag[1], acc, 0, 0, 0);
            ushort4 pk;
            pk.x = f2bf(acc[0] * dv);
            pk.y = f2bf(acc[1] * dv);
            pk.z = f2bf(acc[2] * dv);
            pk.w = f2bf(acc[3] * dv);
            *(ushort4*)(hb + (size_t)(row0 + m) * DIM + nt * 16 + quad * 4) = pk;
        }
    }
}

// ---------------- gather: 4 nodes/wave, 16-edge MLP, sv prefetch ----------
__global__ void __launch_bounds__(256)
gather_kernel(const int* __restrict__ rowbeg, const int* __restrict__ rowend,
              const unsigned int* __restrict__ srt, const unsigned short* __restrict__ hb,
              const float* __restrict__ dinv, unsigned short* __restrict__ hbout,
              float* __restrict__ gstatRep, int N) {
    __shared__ float red[2][4][64];
    int lane = threadIdx.x & 63;
    int wv   = threadIdx.x >> 6;
    int g    = blockIdx.x * 4 + wv;
    int n0   = g << 2;
    float s_sum = 0.f, s_sq = 0.f;

    if (n0 < N) {  // uniform per wave; N % 4 == 0; groups never straddle buckets
        int beg = __builtin_amdgcn_readfirstlane(rowbeg[n0]);
        int s1  = __builtin_amdgcn_readfirstlane(rowbeg[n0 + 1]);
        int s2  = __builtin_amdgcn_readfirstlane(rowbeg[n0 + 2]);
        int s3  = __builtin_amdgcn_readfirstlane(rowbeg[n0 + 3]);
        int end = __builtin_amdgcn_readfirstlane(rowend[n0 + 3]);
        float acc0 = 0.f, acc1 = 0.f, acc2 = 0.f, acc3 = 0.f;

        unsigned int sv = (beg + lane < end) ? srt[beg + lane] : 0u;
        for (int base = beg; base < end; base += 64) {
            // prefetch next index batch before consuming this one
            int nidx = base + 64 + lane;
            unsigned int sv_next = (nidx < end) ? srt[nidx] : 0u;
            int cn = min(64, end - base);                   // multiple of 8
            int j = 0;
            for (; j + 16 <= cn; j += 16) {                 // double chunk
                int pA = base + j;                          // uniform (SALU)
                int pB = pA + 8;
                int kA = (pA >= s1) + (pA >= s2) + (pA >= s3);
                int kB = (pB >= s1) + (pB >= s2) + (pB >= s3);
                float v[16];
#pragma unroll
                for (int u = 0; u < 16; ++u) {              // 16 loads in flight
                    unsigned int s = (unsigned)__builtin_amdgcn_readlane((int)sv, j + u);
                    v[u] = bf2f(hb[(size_t)s * DIM + lane]);
                }
                float cA = ((v[0] + v[1]) + (v[2] + v[3])) +
                           ((v[4] + v[5]) + (v[6] + v[7]));
                float cB = ((v[8] + v[9]) + (v[10] + v[11])) +
                           ((v[12] + v[13]) + (v[14] + v[15]));
                acc0 += (kA == 0) ? cA : 0.f;
                acc1 += (kA == 1) ? cA : 0.f;
                acc2 += (kA == 2) ? cA : 0.f;
                acc3 += (kA == 3) ? cA : 0.f;
                acc0 += (kB == 0) ? cB : 0.f;
                acc1 += (kB == 1) ? cB : 0.f;
                acc2 += (kB == 2) ? cB : 0.f;
                acc3 += (kB == 3) ? cB : 0.f;
            }
            for (; j < cn; j += 8) {                        // odd tail chunk
                int p0 = base + j;
                int k = (p0 >= s1) + (p0 >= s2) + (p0 >= s3);
                float v[8];
#pragma unroll
                for (int u = 0; u < 8; ++u) {
                    unsigned int s = (unsigned)__builtin_amdgcn_readlane((int)sv, j + u);
                    v[u] = bf2f(hb[(size_t)s * DIM + lane]);
                }
                float csum = ((v[0] + v[1]) + (v[2] + v[3])) +
                             ((v[4] + v[5]) + (v[6] + v[7]));
                acc0 += (k == 0) ? csum : 0.f;
                acc1 += (k == 1) ? csum : 0.f;
                acc2 += (k == 2) ? csum : 0.f;
                acc3 += (k == 3) ? csum : 0.f;
            }
            sv = sv_next;
        }

        float v0 = (acc0 + bf2f(hb[(size_t)(n0 + 0) * DIM + lane])) * dinv[n0 + 0];
        float v1 = (acc1 + bf2f(hb[(size_t)(n0 + 1) * DIM + lane])) * dinv[n0 + 1];
        float v2 = (acc2 + bf2f(hb[(size_t)(n0 + 2) * DIM + lane])) * dinv[n0 + 2];
        float v3 = (acc3 + bf2f(hb[(size_t)(n0 + 3) * DIM + lane])) * dinv[n0 + 3];
        unsigned short r0 = f2bf(v0), r1 = f2bf(v1), r2 = f2bf(v2), r3 = f2bf(v3);
        hbout[(size_t)(n0 + 0) * DIM + lane] = r0;
        hbout[(size_t)(n0 + 1) * DIM + lane] = r1;
        hbout[(size_t)(n0 + 2) * DIM + lane] = r2;
        hbout[(size_t)(n0 + 3) * DIM + lane] = r3;
        // stats on the ROUNDED values -> BN transform is exact w.r.t. input
        float w0 = bf2f(r0), w1 = bf2f(r1), w2 = bf2f(r2), w3 = bf2f(r3);
        s_sum = ((w0 + w1) + (w2 + w3));
        s_sq  = ((w0 * w0 + w1 * w1) + (w2 * w2 + w3 * w3));
    }

    red[0][wv][lane] = s_sum;
    red[1][wv][lane] = s_sq;
    __syncthreads();
    if (threadIdx.x < 128) {
        int c = threadIdx.x & 63;
        int which = threadIdx.x >> 6;     // 0 = sum, 1 = sumsq
        float v = red[which][0][c] + red[which][1][c] + red[which][2][c] + red[which][3][c];
        float* dst = gstatRep + (size_t)(blockIdx.x & (NREP - 1)) * 128 + which * 64 + c;
        atomicAdd(dst, v);
    }
}

// ---------------- finish: fold NREP stat copies + BN + ReLU ---------------
// bias b cancels in BN (uniform per-column shift), so it's omitted entirely.
__global__ void __launch_bounds__(256)
finish_kernel(const ushort4* __restrict__ hbo, float4* __restrict__ out,
              const float* __restrict__ gstatRep,
              const float* __restrict__ gamma, const float* __restrict__ beta,
              int total4, int N) {
    __shared__ float scale[64];
    __shared__ float shift[64];
    __shared__ float stat[128];
    int t = threadIdx.x;
    if (t < 128) {
        int c = t & 63;
        int which = t >> 6;
        float acc = 0.f;
#pragma unroll
        for (int r = 0; r < NREP; ++r)
            acc += gstatRep[(size_t)r * 128 + which * 64 + c];
        stat[t] = acc;
    }
    __syncthreads();
    if (t < 64) {
        float invN = 1.0f / (float)N;
        float mean = stat[t] * invN;
        float var  = stat[64 + t] * invN - mean * mean;
        float sc   = gamma[t] * rsqrtf(var + BN_EPS);
        scale[t] = sc;
        shift[t] = beta[t] - mean * sc;
    }
    __syncthreads();
    int i = blockIdx.x * blockDim.x + t;
    if (i >= total4) return;
    int c = (i * 4) & 63;
    ushort4 u = hbo[i];
    float4 v;
    float a0 = fmaf(bf2f(u.x), scale[c],     shift[c]);
    float a1 = fmaf(bf2f(u.y), scale[c + 1], shift[c + 1]);
    float a2 = fmaf(bf2f(u.z), scale[c + 2], shift[c + 2]);
    float a3 = fmaf(bf2f(u.w), scale[c + 3], shift[c + 3]);
    v.x = a0 > 0.f ? a0 : 0.f;
    v.y = a1 > 0.f ? a1 : 0.f;
    v.z = a2 > 0.f ? a2 : 0.f;
    v.w = a3 > 0.f ? a3 : 0.f;
    out[i] = v;
}

extern "C" void kernel_launch(void* const* d_in, const int* in_sizes, int n_in,
                              void* d_out, int out_size, void* d_ws, size_t ws_size,
                              hipStream_t stream) {
    const float* x     = (const float*)d_in[0];          // [N, 64]
    const int*   eidx  = (const int*)d_in[1];            // [2, E]
    const float* W     = (const float*)d_in[2];          // [64, 64]
    // d_in[3] = b : cancels in BatchNorm (uniform per-column shift)
    const float* gamma = (const float*)d_in[4];          // [64]
    const float* beta  = (const float*)d_in[5];          // [64]
    float* out = (float*)d_out;                          // [N, 64]

    const int N = N_NODES;
    const int total = N * DIM;

    const int* src = eidx;
    const int* dst = eidx + N_EDGES;

    // workspace layout (byte offsets; hb rows are 128 B)
    char* ws = (char*)d_ws;
    size_t off_hb      = 0;                                   // N*128 = 12,800,000
    size_t off_hbout   = off_hb + (size_t)N * DIM * 2;        // 12,800,000 (pre-BN bf16)
    size_t off_dinv    = off_hbout + (size_t)N * DIM * 2;     // 25,600,000
    size_t off_rowbeg  = off_dinv + (size_t)N * 4;            // 26,000,000
    size_t off_rowend  = off_rowbeg + (size_t)N * 4;          // 26,400,000
    size_t off_entries = off_rowend + (size_t)N * 4;          // 26,800,000
    size_t off_z       = off_entries + (size_t)NBUCK * CAP_OUT * 4;  // 38,010,752 (mult 128)

    unsigned short* hb     = (unsigned short*)(ws + off_hb);
    unsigned short* hbout  = (unsigned short*)(ws + off_hbout);
    float*          dinv   = (float*)(ws + off_dinv);
    int*            rowbeg = (int*)(ws + off_rowbeg);
    int*            rowend = (int*)(ws + off_rowend);
    unsigned int*   entries = (unsigned int*)(ws + off_entries);
    // zero region: dummy hb row [128 B] | cur[NBUCK] | gstatRep[NREP*128]
    int*   cur      = (int*)(ws + off_z + 128);
    float* gstatRep = (float*)(cur + NBUCK);
    int dummyIdx = (int)(off_z / (DIM * 2));             // hb row index of zero block

    size_t zbytes = 128 + (size_t)NBUCK * 4 + (size_t)NREP * 128 * 4;  // 19,640 B
    hipMemsetAsync(ws + off_z, 0, zbytes, stream);

    passA_kernel<<<ABLK, 1024, 0, stream>>>(src, dst, cur, entries, N_EDGES);

    build_kernel<<<NBUCK, 256, 0, stream>>>(entries, cur, rowbeg, rowend, dinv,
                                            x, W, hb, dummyIdx, N);

    gather_kernel<<<GBLK, 256, 0, stream>>>(rowbeg, rowend, entries, hb, dinv,
                                            hbout, gstatRep, N);

    finish_kernel<<<(total / 4 + 255) / 256, 256, 0, stream>>>((const ushort4*)hbout,
                                                               (float4*)out, gstatRep,
                                                               gamma, beta, total / 4, N);
}